// Round 12
// baseline (837.554 us; speedup 1.0000x reference)
//
#include <hip/hip_runtime.h>
#include <hip/hip_bf16.h>
#include <math.h>

#define NODE_DIM  64
#define EDGE_DIM  32
#define NUM_GAUSS 16
#define HIDDEN    128
#define CAT_DIM   160
#define TBL_BINS  2048
#define TBL_SCALE 256.0f                // bins per unit distance (domain [0,8))
#define L1ABSZ    (64 * 256)            // packed W1ab per layer (K=64, N=256)
#define L2SZ      (HIDDEN * NODE_DIM)   // packed W2 per layer   (K=128, N=64)
#define TBLSZ     (2 * TBL_BINS * 128)  // per-layer edge-attr table entries

typedef __attribute__((ext_vector_type(8))) short short8;
typedef __attribute__((ext_vector_type(4))) float float4v;

static __device__ __forceinline__ short f2bf(float x) {
  __hip_bfloat16 h = __float2bfloat16(x);
  return *reinterpret_cast<short*>(&h);
}
static __device__ __forceinline__ float bflo(unsigned u) { return __uint_as_float(u << 16); }
static __device__ __forceinline__ float bfhi(unsigned u) { return __uint_as_float(u & 0xffff0000u); }

// ---------------- init: h_f32 = embed[atoms], h_bf16 mirror ----------------
__global__ void k_init(const int* __restrict__ atoms, const float* __restrict__ embed_w,
                       float* __restrict__ hf, short* __restrict__ hb, int n) {
  int stride = gridDim.x * blockDim.x;
  for (int i = blockIdx.x * blockDim.x + threadIdx.x; i < n; i += stride) {
    float f = embed_w[atoms[i >> 6] * NODE_DIM + (i & 63)];
    hf[i] = f;
    hb[i] = f2bf(f);
  }
}

__global__ void k_zero_f(float* __restrict__ p, int n) {
  int stride = gridDim.x * blockDim.x;
  for (int i = blockIdx.x * blockDim.x + threadIdx.x; i < n; i += stride) p[i] = 0.f;
}
__global__ void k_zero_i(int* __restrict__ p, int n) {
  int i = blockIdx.x * blockDim.x + threadIdx.x;
  if (i < n) p[i] = 0;
}

// ---------------- edge precompute: ety = (kind<<11) | bin(dist); fused dst histogram ----------------
__global__ void k_edge_pre(const int* __restrict__ src, const int* __restrict__ dst,
                           const float* __restrict__ coords, const int* __restrict__ isr,
                           int* __restrict__ ety, int* __restrict__ counts, int E) {
  int stride = gridDim.x * blockDim.x;
  for (int e = blockIdx.x * blockDim.x + threadIdx.x; e < E; e += stride) {
    int s = src[e], d = dst[e];
    float dx = coords[s*3+0] - coords[d*3+0];
    float dy = coords[s*3+1] - coords[d*3+1];
    float dz = coords[s*3+2] - coords[d*3+2];
    float dist = sqrtf(dx*dx + dy*dy + dz*dz);
    int bin = (int)(dist * TBL_SCALE);
    bin = (bin > TBL_BINS - 1) ? TBL_BINS - 1 : bin;
    int kind = (isr[s] != isr[d]) ? 1 : 0;
    ety[e] = (kind << 11) | bin;
    atomicAdd(&counts[d], 1);
  }
}

// ---------------- edge-attr table: tbl[l][kind][bin][col] = rbf(bin)@W1c + sub_w[kind]@W1c ----------------
__global__ void k_tbl(const float* __restrict__ W1, const float* __restrict__ sub_w,
                      short* __restrict__ tbl, int total) {
  int idx = blockIdx.x * 256 + threadIdx.x;   // thread per (l, kind, bin)
  if (idx >= total) return;
  int bin  = idx & (TBL_BINS - 1);
  int kind = (idx >> 11) & 1;
  int l    = idx >> 12;
  float dist = ((float)bin + 0.5f) * (1.0f / TBL_SCALE);
  float rbf[16], skv[16];
  #pragma unroll
  for (int g = 0; g < 16; ++g) {
    float t = dist - (float)g * (1.0f / 3.0f);
    rbf[g] = __expf(-4.5f * t * t);
    skv[g] = sub_w[kind * 16 + g];
  }
  const float* W1c = W1 + (size_t)l * CAT_DIM * HIDDEN + 128 * HIDDEN;
  short* outp = tbl + ((size_t)idx) * 128;
  #pragma unroll 4
  for (int col = 0; col < 128; ++col) {
    float acc = 0.f;
    #pragma unroll
    for (int g = 0; g < 16; ++g) acc += rbf[g] * W1c[g * 128 + col];
    #pragma unroll
    for (int g = 0; g < 16; ++g) acc += skv[g] * W1c[(16 + g) * 128 + col];
    outp[col] = f2bf(acc);
  }
}

// ---------------- CSR build ----------------
__global__ void k_scan_part(const int* __restrict__ counts, int* __restrict__ part, int N) {
  __shared__ int red[256];
  int t = threadIdx.x;
  int i = blockIdx.x * 256 + t;
  red[t] = (i < N) ? counts[i] : 0;
  __syncthreads();
  for (int o = 128; o > 0; o >>= 1) {
    if (t < o) red[t] += red[t + o];
    __syncthreads();
  }
  if (t == 0) part[blockIdx.x] = red[0];
}

__global__ void k_scan_top(int* __restrict__ part, int nb) {
  __shared__ int s[512];
  int t = threadIdx.x;
  int v = (t < nb) ? part[t] : 0;
  s[t] = v;
  __syncthreads();
  for (int o = 1; o < 512; o <<= 1) {
    int u = (t >= o) ? s[t - o] : 0;
    __syncthreads();
    s[t] += u;
    __syncthreads();
  }
  if (t < nb) part[t] = s[t] - v;   // exclusive
}

// apply: cursor = colptr = exclusive prefix; colptr[N] = E
__global__ void k_scan_apply(const int* __restrict__ counts, const int* __restrict__ part,
                             int* __restrict__ cursor, int* __restrict__ colptr,
                             int N, int E) {
  __shared__ int s[256];
  int t = threadIdx.x;
  int i = blockIdx.x * 256 + t;
  int v = (i < N) ? counts[i] : 0;
  s[t] = v;
  __syncthreads();
  for (int o = 1; o < 256; o <<= 1) {
    int u = (t >= o) ? s[t - o] : 0;
    __syncthreads();
    s[t] += u;
    __syncthreads();
  }
  if (i < N) {
    int ex = part[blockIdx.x] + s[t] - v;   // exclusive prefix
    cursor[i] = ex;
    colptr[i] = ex;
    if (i == N - 1) colptr[N] = E;
  }
}

// scatter (src, ety) into dst-sorted order (per-node cursor, 100k counters: low contention)
__global__ void k_build(const int* __restrict__ src, const int* __restrict__ dst,
                        const int* __restrict__ ety, int* __restrict__ cursor,
                        int2* __restrict__ sd_p, int E) {
  int stride = gridDim.x * blockDim.x;
  for (int e = blockIdx.x * blockDim.x + threadIdx.x; e < E; e += stride) {
    int d = dst[e];
    int p = atomicAdd(&cursor[d], 1);
    sd_p[p] = make_int2(src[e], ety[e]);
  }
}

// ---------------- weight packing (B-fragment order: ((kt*4+quad)*N + n)*8 + j) ----------------
__global__ void k_pack_w1ab(const float* __restrict__ W1, short* __restrict__ Wp, int total) {
  int i = blockIdx.x * blockDim.x + threadIdx.x;
  if (i >= total) return;
  int l = i / L1ABSZ, r = i % L1ABSZ;
  int k = r / 256, n = r % 256;
  int kt = k >> 5, quad = (k >> 3) & 3, j = k & 7;
  int srow = (n < 128) ? k : 64 + k;
  int scol = (n < 128) ? n : n - 128;
  Wp[l * L1ABSZ + ((kt*4 + quad) * 256 + n) * 8 + j] =
      f2bf(W1[(size_t)l * CAT_DIM * HIDDEN + srow * HIDDEN + scol]);
}
__global__ void k_pack_w2(const float* __restrict__ W, short* __restrict__ Wp, int total) {
  int i = blockIdx.x * blockDim.x + threadIdx.x;
  if (i >= total) return;
  int l = i / L2SZ, r = i % L2SZ;
  int k = r / NODE_DIM, n = r % NODE_DIM;
  int kt = k >> 5, quad = (k >> 3) & 3, j = k & 7;
  Wp[l * L2SZ + ((kt*4 + quad) * NODE_DIM + n) * 8 + j] = f2bf(W[i]);
}

// ---------------- node kernel: [agg=Sb@W2+cnt*b2; h=relu(h+agg)] ; [pa|pb = h@W1ab] ----------------
__global__ __launch_bounds__(256, 4) void k_node(
    float* __restrict__ hf, const short* __restrict__ hb,
    const short* __restrict__ Sb, const int* __restrict__ cnts,
    const short* __restrict__ W2p, const float* __restrict__ b2,
    const short* __restrict__ W1abp, const float* __restrict__ b1,
    short* __restrict__ pa, short* __restrict__ pb, int N)
{
  __shared__ short ht[64 * 72];

  const int tid  = threadIdx.x;
  const int lane = tid & 63;
  const int w    = tid >> 6;
  const int quad = lane >> 4;
  const int l16  = lane & 15;
  const int base = blockIdx.x * 64 + w * 16;

  if (W2p) {
    float4v acc[4];
    #pragma unroll
    for (int nt = 0; nt < 4; ++nt) acc[nt] = (float4v)0.f;
    const int arow = base + l16;
    const bool av = arow < N;
    #pragma unroll
    for (int kt = 0; kt < 4; ++kt) {
      short8 a = av ? *(const short8*)&Sb[(size_t)arow * 128 + kt*32 + quad*8]
                    : (short8)0;
      #pragma unroll
      for (int nt = 0; nt < 4; ++nt) {
        short8 b = *(const short8*)&W2p[((kt*4 + quad) * NODE_DIM + nt*16 + l16) * 8];
        acc[nt] = __builtin_amdgcn_mfma_f32_16x16x32_bf16(a, b, acc[nt], 0, 0, 0);
      }
    }
    float cf[4];
    #pragma unroll
    for (int r = 0; r < 4; ++r) {
      int row = base + quad*4 + r;
      cf[r] = (row < N) ? (float)cnts[row] : 0.f;
    }
    #pragma unroll
    for (int nt = 0; nt < 4; ++nt) {
      int col = nt*16 + l16;
      float bb = b2[col];
      #pragma unroll
      for (int r = 0; r < 4; ++r) {
        int row = base + quad*4 + r;
        int lrow = w*16 + quad*4 + r;
        if (row < N) {
          float v = hf[(size_t)row * 64 + col] + acc[nt][r] + cf[r] * bb;
          v = fmaxf(v, 0.f);
          hf[(size_t)row * 64 + col] = v;
          ht[lrow * 72 + col] = f2bf(v);
        } else {
          ht[lrow * 72 + col] = 0;
        }
      }
    }
  } else {
    int row = base + l16;
    #pragma unroll
    for (int c = 0; c < 2; ++c) {
      int colc = quad*16 + c*8;
      short8 v = (row < N) ? *(const short8*)&hb[(size_t)row * 64 + colc] : (short8)0;
      *(short8*)&ht[(w*16 + l16) * 72 + colc] = v;
    }
  }

  if (W1abp) {
    float4v acc[16];
    #pragma unroll
    for (int nt = 0; nt < 16; ++nt) acc[nt] = (float4v)0.f;
    #pragma unroll
    for (int kt = 0; kt < 2; ++kt) {
      short8 a = *(const short8*)&ht[(w*16 + l16) * 72 + kt*32 + quad*8];
      #pragma unroll
      for (int nt = 0; nt < 16; ++nt) {
        short8 b = *(const short8*)&W1abp[((kt*4 + quad) * 256 + nt*16 + l16) * 8];
        acc[nt] = __builtin_amdgcn_mfma_f32_16x16x32_bf16(a, b, acc[nt], 0, 0, 0);
      }
    }
    #pragma unroll
    for (int nt = 0; nt < 16; ++nt) {
      int col = nt*16 + l16;
      float bb = (col < 128) ? b1[col] : 0.f;
      #pragma unroll
      for (int r = 0; r < 4; ++r) {
        int row = base + quad*4 + r;
        if (row < N) {
          float v = acc[nt][r] + bb;
          if (col < 128) pa[(size_t)row * 128 + col]         = f2bf(v);
          else           pb[(size_t)row * 128 + (col - 128)] = f2bf(v);
        }
      }
    }
  }
}

// ---------------- gather kernel: wave per node, 8-deep double-buffered CSR gather ----------------
__global__ __launch_bounds__(256, 8) void k_gather(
    const short* __restrict__ pa, const short* __restrict__ pb,
    const short* __restrict__ tblL,
    const int2* __restrict__ sd_p, const int* __restrict__ colptr,
    short* __restrict__ Sb, int N)
{
  int n = blockIdx.x * 4 + (threadIdx.x >> 6);
  if (n >= N) return;
  const int lane = threadIdx.x & 63;
  const int d2 = lane * 2;

  const int s = colptr[n];
  const int e = colptr[n + 1];

  unsigned up = *(const unsigned*)&pa[(size_t)n * 128 + d2];
  const float p0 = bflo(up), p1 = bfhi(up);
  float s0 = 0.f, s1 = 0.f;

  if (e > s) {
    unsigned ub0[8], ue0[8], ub1[8], ue1[8];

    auto load8 = [&](unsigned (&ub)[8], unsigned (&ue)[8], int j) {
      #pragma unroll
      for (int t = 0; t < 8; ++t) {
        int jj = (j + t < e) ? j + t : s;     // clamp: always a valid record
        int2 r = sd_p[jj];                     // wave-uniform address (broadcast)
        ub[t] = *(const unsigned*)&pb[(size_t)r.x * 128 + d2];
        ue[t] = *(const unsigned*)&tblL[(size_t)r.y * 128 + d2];
      }
    };
    auto consume8 = [&](unsigned (&ub)[8], unsigned (&ue)[8], int j) {
      #pragma unroll
      for (int t = 0; t < 8; ++t) {
        if (j + t < e) {
          float x0 = p0 + bflo(ub[t]) + bflo(ue[t]);
          float x1 = p1 + bfhi(ub[t]) + bfhi(ue[t]);
          s0 += x0 * __builtin_amdgcn_rcpf(1.f + __expf(-x0));
          s1 += x1 * __builtin_amdgcn_rcpf(1.f + __expf(-x1));
        }
      }
    };

    load8(ub0, ue0, s);
    for (int j = s; j < e; j += 16) {
      if (j + 8 < e) load8(ub1, ue1, j + 8);
      consume8(ub0, ue0, j);
      if (j + 8 < e) {
        if (j + 16 < e) load8(ub0, ue0, j + 16);
        consume8(ub1, ue1, j + 8);
      }
    }
  }

  unsigned pk = ((unsigned)(unsigned short)f2bf(s1) << 16) | (unsigned short)f2bf(s0);
  *(unsigned*)&Sb[(size_t)n * 128 + d2] = pk;
}

// ---------------- mean pool (batch_ids sorted): wave per 64 nodes ----------------
__global__ void k_pool(const float* __restrict__ h, const int* __restrict__ batch_ids,
                       float* __restrict__ pooled, float* __restrict__ counts, int N) {
  int lane = threadIdx.x & 63;
  int base = blockIdx.x * 64;
  float acc = 0.f;
  int   cnt = 0;
  int  gcur = -1;
  for (int n = 0; n < 64; ++n) {
    int node = base + n;
    if (node >= N) break;
    int g = batch_ids[node];
    if (g != gcur) {
      if (gcur >= 0) {
        atomicAdd(&pooled[gcur * NODE_DIM + lane], acc);
        if (lane == 0) atomicAdd(&counts[gcur], (float)cnt);
      }
      gcur = g; acc = 0.f; cnt = 0;
    }
    acc += h[(size_t)node * NODE_DIM + lane];
    cnt++;
  }
  if (gcur >= 0) {
    atomicAdd(&pooled[gcur * NODE_DIM + lane], acc);
    if (lane == 0) atomicAdd(&counts[gcur], (float)cnt);
  }
}

__global__ void k_final(const float* __restrict__ pooled, const float* __restrict__ counts,
                        const float* __restrict__ fc_w, const float* __restrict__ fc_b,
                        float* __restrict__ out, int G) {
  int g = blockIdx.x * blockDim.x + threadIdx.x;
  if (g < G) {
    float acc = 0.f;
    for (int d = 0; d < NODE_DIM; ++d) acc += pooled[g * NODE_DIM + d] * fc_w[d];
    float c = counts[g];
    if (c < 1.f) c = 1.f;
    out[g] = acc / c + fc_b[0];
  }
}

extern "C" void kernel_launch(void* const* d_in, const int* in_sizes, int n_in,
                              void* d_out, int out_size, void* d_ws, size_t ws_size,
                              hipStream_t stream) {
  const int*   atoms   = (const int*)  d_in[0];
  const int*   eidx    = (const int*)  d_in[1];
  const float* coords  = (const float*)d_in[2];
  const int*   isr     = (const int*)  d_in[3];
  const int*   batch   = (const int*)  d_in[4];
  const float* embed_w = (const float*)d_in[5];
  const float* sub_w   = (const float*)d_in[6];
  const float* W1      = (const float*)d_in[7];
  const float* b1      = (const float*)d_in[8];
  const float* W2      = (const float*)d_in[9];
  const float* b2      = (const float*)d_in[10];
  const float* fc_w    = (const float*)d_in[11];
  const float* fc_b    = (const float*)d_in[12];
  float* out = (float*)d_out;

  const int N = in_sizes[0];
  const int E = in_sizes[1] / 2;
  const int L = in_sizes[8] / HIDDEN;
  const int G = out_size;

  const int* srcv = eidx;
  const int* dstv = eidx + E;

  size_t off = 0;
  auto carve = [&](size_t bytes) -> char* {
    char* p = (char*)d_ws + off;
    off += (bytes + 255) & ~(size_t)255;
    return p;
  };
  float* hf     = (float*)carve((size_t)N * NODE_DIM * 4);
  short* hb     = (short*)carve((size_t)N * NODE_DIM * 2);
  short* Sb     = (short*)carve((size_t)N * HIDDEN * 2);
  short* pa     = (short*)carve((size_t)N * HIDDEN * 2);
  short* pb     = (short*)carve((size_t)N * HIDDEN * 2);
  int*   ety    = (int*)  carve((size_t)E * 4);
  int*   cnts   = (int*)  carve((size_t)N * 4);
  int*   cursor = (int*)  carve((size_t)N * 4);
  int*   colptr = (int*)  carve(((size_t)N + 2) * 4);
  int2*  sd_p   = (int2*) carve((size_t)E * 8);
  int*   part   = (int*)  carve(((size_t)N / 256 + 2) * 4);
  short* W1abp  = (short*)carve((size_t)L * L1ABSZ * 2);
  short* W2p    = (short*)carve((size_t)L * L2SZ * 2);
  short* tbl    = (short*)carve((size_t)L * TBLSZ * 2);
  float* pooled = (float*)carve((size_t)G * NODE_DIM * 4);
  float* cntg   = (float*)carve((size_t)G * 4);

  const int nbN = (N + 255) / 256;

  k_zero_i<<<nbN, 256, 0, stream>>>(cnts, N);
  k_init<<<1024, 256, 0, stream>>>(atoms, embed_w, hf, hb, N * NODE_DIM);
  k_edge_pre<<<1024, 256, 0, stream>>>(srcv, dstv, coords, isr, ety, cnts, E);
  k_zero_f<<<(G * NODE_DIM + G + 255) / 256, 256, 0, stream>>>(pooled, G * NODE_DIM + G);
  k_scan_part<<<nbN, 256, 0, stream>>>(cnts, part, N);
  k_scan_top<<<1, 512, 0, stream>>>(part, nbN);
  k_scan_apply<<<nbN, 256, 0, stream>>>(cnts, part, cursor, colptr, N, E);
  k_build<<<1024, 256, 0, stream>>>(srcv, dstv, ety, cursor, sd_p, E);
  k_pack_w1ab<<<(L * L1ABSZ + 255) / 256, 256, 0, stream>>>(W1, W1abp, L * L1ABSZ);
  k_pack_w2<<<(L * L2SZ + 255) / 256, 256, 0, stream>>>(W2, W2p, L * L2SZ);
  k_tbl<<<(L * 2 * TBL_BINS + 255) / 256, 256, 0, stream>>>(W1, sub_w, tbl, L * 2 * TBL_BINS);

  const int nblk_n = (N + 63) / 64;
  const int nblk_g = (N + 3) / 4;
  for (int l = 0; l < L; ++l) {
    k_node<<<nblk_n, 256, 0, stream>>>(
        hf, hb, Sb, cnts,
        (l > 0) ? W2p + (size_t)(l - 1) * L2SZ : (const short*)nullptr,
        (l > 0) ? b2 + (size_t)(l - 1) * NODE_DIM : (const float*)nullptr,
        W1abp + (size_t)l * L1ABSZ, b1 + (size_t)l * HIDDEN,
        pa, pb, N);
    k_gather<<<nblk_g, 256, 0, stream>>>(pa, pb, tbl + (size_t)l * TBLSZ,
                                         sd_p, colptr, Sb, N);
  }
  k_node<<<nblk_n, 256, 0, stream>>>(
      hf, hb, Sb, cnts,
      W2p + (size_t)(L - 1) * L2SZ, b2 + (size_t)(L - 1) * NODE_DIM,
      (const short*)nullptr, (const float*)nullptr, pa, pb, N);

  k_pool<<<(N + 63) / 64, 64, 0, stream>>>(hf, batch, pooled, cntg, N);
  k_final<<<1, 64, 0, stream>>>(pooled, cntg, fc_w, fc_b, out, G);
}

// Round 13
// 767.995 us; speedup vs baseline: 1.0906x; 1.0906x over previous
//
#include <hip/hip_runtime.h>
#include <hip/hip_bf16.h>
#include <math.h>

#define NODE_DIM  64
#define EDGE_DIM  32
#define NUM_GAUSS 16
#define HIDDEN    128
#define CAT_DIM   160
#define TBL_BINS  2048
#define TBL_SCALE 256.0f                // bins per unit distance (domain [0,8))
#define L1ABSZ    (64 * 256)            // packed W1ab per layer (K=64, N=256)
#define L2SZ      (HIDDEN * NODE_DIM)   // packed W2 per layer   (K=128, N=64)
#define TBLSZ     (2 * TBL_BINS * 128)  // per-layer edge-attr table entries

typedef __attribute__((ext_vector_type(8))) short short8;
typedef __attribute__((ext_vector_type(4))) float float4v;

static __device__ __forceinline__ short f2bf(float x) {
  __hip_bfloat16 h = __float2bfloat16(x);
  return *reinterpret_cast<short*>(&h);
}
static __device__ __forceinline__ float bflo(unsigned u) { return __uint_as_float(u << 16); }
static __device__ __forceinline__ float bfhi(unsigned u) { return __uint_as_float(u & 0xffff0000u); }

// ---------------- init: h_f32 = embed[atoms], h_bf16 mirror ----------------
__global__ void k_init(const int* __restrict__ atoms, const float* __restrict__ embed_w,
                       float* __restrict__ hf, short* __restrict__ hb, int n) {
  int stride = gridDim.x * blockDim.x;
  for (int i = blockIdx.x * blockDim.x + threadIdx.x; i < n; i += stride) {
    float f = embed_w[atoms[i >> 6] * NODE_DIM + (i & 63)];
    hf[i] = f;
    hb[i] = f2bf(f);
  }
}

__global__ void k_zero_f(float* __restrict__ p, int n) {
  int stride = gridDim.x * blockDim.x;
  for (int i = blockIdx.x * blockDim.x + threadIdx.x; i < n; i += stride) p[i] = 0.f;
}
__global__ void k_zero_i(int* __restrict__ p, int n) {
  int i = blockIdx.x * blockDim.x + threadIdx.x;
  if (i < n) p[i] = 0;
}

// ---------------- edge precompute: ety = (kind<<11) | bin(dist); fused dst histogram ----------------
__global__ void k_edge_pre(const int* __restrict__ src, const int* __restrict__ dst,
                           const float* __restrict__ coords, const int* __restrict__ isr,
                           int* __restrict__ ety, int* __restrict__ counts, int E) {
  int stride = gridDim.x * blockDim.x;
  for (int e = blockIdx.x * blockDim.x + threadIdx.x; e < E; e += stride) {
    int s = src[e], d = dst[e];
    float dx = coords[s*3+0] - coords[d*3+0];
    float dy = coords[s*3+1] - coords[d*3+1];
    float dz = coords[s*3+2] - coords[d*3+2];
    float dist = sqrtf(dx*dx + dy*dy + dz*dz);
    int bin = (int)(dist * TBL_SCALE);
    bin = (bin > TBL_BINS - 1) ? TBL_BINS - 1 : bin;
    int kind = (isr[s] != isr[d]) ? 1 : 0;
    ety[e] = (kind << 11) | bin;
    atomicAdd(&counts[d], 1);
  }
}

// ---------------- edge-attr table: tbl[l][kind][bin][col] = rbf(bin)@W1c + sub_w[kind]@W1c ----------------
__global__ void k_tbl(const float* __restrict__ W1, const float* __restrict__ sub_w,
                      short* __restrict__ tbl, int total) {
  int idx = blockIdx.x * 256 + threadIdx.x;   // thread per (l, kind, bin)
  if (idx >= total) return;
  int bin  = idx & (TBL_BINS - 1);
  int kind = (idx >> 11) & 1;
  int l    = idx >> 12;
  float dist = ((float)bin + 0.5f) * (1.0f / TBL_SCALE);
  float rbf[16], skv[16];
  #pragma unroll
  for (int g = 0; g < 16; ++g) {
    float t = dist - (float)g * (1.0f / 3.0f);
    rbf[g] = __expf(-4.5f * t * t);
    skv[g] = sub_w[kind * 16 + g];
  }
  const float* W1c = W1 + (size_t)l * CAT_DIM * HIDDEN + 128 * HIDDEN;
  short* outp = tbl + ((size_t)idx) * 128;
  #pragma unroll 4
  for (int col = 0; col < 128; ++col) {
    float acc = 0.f;
    #pragma unroll
    for (int g = 0; g < 16; ++g) acc += rbf[g] * W1c[g * 128 + col];
    #pragma unroll
    for (int g = 0; g < 16; ++g) acc += skv[g] * W1c[(16 + g) * 128 + col];
    outp[col] = f2bf(acc);
  }
}

// ---------------- CSR build ----------------
__global__ void k_scan_part(const int* __restrict__ counts, int* __restrict__ part, int N) {
  __shared__ int red[256];
  int t = threadIdx.x;
  int i = blockIdx.x * 256 + t;
  red[t] = (i < N) ? counts[i] : 0;
  __syncthreads();
  for (int o = 128; o > 0; o >>= 1) {
    if (t < o) red[t] += red[t + o];
    __syncthreads();
  }
  if (t == 0) part[blockIdx.x] = red[0];
}

__global__ void k_scan_top(int* __restrict__ part, int nb) {
  __shared__ int s[512];
  int t = threadIdx.x;
  int v = (t < nb) ? part[t] : 0;
  s[t] = v;
  __syncthreads();
  for (int o = 1; o < 512; o <<= 1) {
    int u = (t >= o) ? s[t - o] : 0;
    __syncthreads();
    s[t] += u;
    __syncthreads();
  }
  if (t < nb) part[t] = s[t] - v;   // exclusive
}

// apply: cursor = colptr = exclusive prefix; colptr[N] = E
__global__ void k_scan_apply(const int* __restrict__ counts, const int* __restrict__ part,
                             int* __restrict__ cursor, int* __restrict__ colptr,
                             int N, int E) {
  __shared__ int s[256];
  int t = threadIdx.x;
  int i = blockIdx.x * 256 + t;
  int v = (i < N) ? counts[i] : 0;
  s[t] = v;
  __syncthreads();
  for (int o = 1; o < 256; o <<= 1) {
    int u = (t >= o) ? s[t - o] : 0;
    __syncthreads();
    s[t] += u;
    __syncthreads();
  }
  if (i < N) {
    int ex = part[blockIdx.x] + s[t] - v;   // exclusive prefix
    cursor[i] = ex;
    colptr[i] = ex;
    if (i == N - 1) colptr[N] = E;
  }
}

// scatter (src*256, ety*256) BYTE OFFSETS into dst-sorted order
__global__ void k_build(const int* __restrict__ src, const int* __restrict__ dst,
                        const int* __restrict__ ety, int* __restrict__ cursor,
                        int2* __restrict__ sd_p, int E) {
  int stride = gridDim.x * blockDim.x;
  for (int e = blockIdx.x * blockDim.x + threadIdx.x; e < E; e += stride) {
    int d = dst[e];
    int p = atomicAdd(&cursor[d], 1);
    sd_p[p] = make_int2(src[e] << 8, ety[e] << 8);   // 256 B per row
  }
}

// ---------------- weight packing (B-fragment order: ((kt*4+quad)*N + n)*8 + j) ----------------
__global__ void k_pack_w1ab(const float* __restrict__ W1, short* __restrict__ Wp, int total) {
  int i = blockIdx.x * blockDim.x + threadIdx.x;
  if (i >= total) return;
  int l = i / L1ABSZ, r = i % L1ABSZ;
  int k = r / 256, n = r % 256;
  int kt = k >> 5, quad = (k >> 3) & 3, j = k & 7;
  int srow = (n < 128) ? k : 64 + k;
  int scol = (n < 128) ? n : n - 128;
  Wp[l * L1ABSZ + ((kt*4 + quad) * 256 + n) * 8 + j] =
      f2bf(W1[(size_t)l * CAT_DIM * HIDDEN + srow * HIDDEN + scol]);
}
__global__ void k_pack_w2(const float* __restrict__ W, short* __restrict__ Wp, int total) {
  int i = blockIdx.x * blockDim.x + threadIdx.x;
  if (i >= total) return;
  int l = i / L2SZ, r = i % L2SZ;
  int k = r / NODE_DIM, n = r % NODE_DIM;
  int kt = k >> 5, quad = (k >> 3) & 3, j = k & 7;
  Wp[l * L2SZ + ((kt*4 + quad) * NODE_DIM + n) * 8 + j] = f2bf(W[i]);
}

// ---------------- node kernel: [agg=Sb@W2+cnt*b2; h=relu(h+agg)] ; [pa|pb = h@W1ab] ----------------
__global__ __launch_bounds__(256, 4) void k_node(
    float* __restrict__ hf, const short* __restrict__ hb,
    const short* __restrict__ Sb, const int* __restrict__ cnts,
    const short* __restrict__ W2p, const float* __restrict__ b2,
    const short* __restrict__ W1abp, const float* __restrict__ b1,
    short* __restrict__ pa, short* __restrict__ pb, int N)
{
  __shared__ short ht[64 * 72];

  const int tid  = threadIdx.x;
  const int lane = tid & 63;
  const int w    = tid >> 6;
  const int quad = lane >> 4;
  const int l16  = lane & 15;
  const int base = blockIdx.x * 64 + w * 16;

  if (W2p) {
    float4v acc[4];
    #pragma unroll
    for (int nt = 0; nt < 4; ++nt) acc[nt] = (float4v)0.f;
    const int arow = base + l16;
    const bool av = arow < N;
    #pragma unroll
    for (int kt = 0; kt < 4; ++kt) {
      short8 a = av ? *(const short8*)&Sb[(size_t)arow * 128 + kt*32 + quad*8]
                    : (short8)0;
      #pragma unroll
      for (int nt = 0; nt < 4; ++nt) {
        short8 b = *(const short8*)&W2p[((kt*4 + quad) * NODE_DIM + nt*16 + l16) * 8];
        acc[nt] = __builtin_amdgcn_mfma_f32_16x16x32_bf16(a, b, acc[nt], 0, 0, 0);
      }
    }
    float cf[4];
    #pragma unroll
    for (int r = 0; r < 4; ++r) {
      int row = base + quad*4 + r;
      cf[r] = (row < N) ? (float)cnts[row] : 0.f;
    }
    #pragma unroll
    for (int nt = 0; nt < 4; ++nt) {
      int col = nt*16 + l16;
      float bb = b2[col];
      #pragma unroll
      for (int r = 0; r < 4; ++r) {
        int row = base + quad*4 + r;
        int lrow = w*16 + quad*4 + r;
        if (row < N) {
          float v = hf[(size_t)row * 64 + col] + acc[nt][r] + cf[r] * bb;
          v = fmaxf(v, 0.f);
          hf[(size_t)row * 64 + col] = v;
          ht[lrow * 72 + col] = f2bf(v);
        } else {
          ht[lrow * 72 + col] = 0;
        }
      }
    }
  } else {
    int row = base + l16;
    #pragma unroll
    for (int c = 0; c < 2; ++c) {
      int colc = quad*16 + c*8;
      short8 v = (row < N) ? *(const short8*)&hb[(size_t)row * 64 + colc] : (short8)0;
      *(short8*)&ht[(w*16 + l16) * 72 + colc] = v;
    }
  }

  if (W1abp) {
    float4v acc[16];
    #pragma unroll
    for (int nt = 0; nt < 16; ++nt) acc[nt] = (float4v)0.f;
    #pragma unroll
    for (int kt = 0; kt < 2; ++kt) {
      short8 a = *(const short8*)&ht[(w*16 + l16) * 72 + kt*32 + quad*8];
      #pragma unroll
      for (int nt = 0; nt < 16; ++nt) {
        short8 b = *(const short8*)&W1abp[((kt*4 + quad) * 256 + nt*16 + l16) * 8];
        acc[nt] = __builtin_amdgcn_mfma_f32_16x16x32_bf16(a, b, acc[nt], 0, 0, 0);
      }
    }
    #pragma unroll
    for (int nt = 0; nt < 16; ++nt) {
      int col = nt*16 + l16;
      float bb = (col < 128) ? b1[col] : 0.f;
      #pragma unroll
      for (int r = 0; r < 4; ++r) {
        int row = base + quad*4 + r;
        if (row < N) {
          float v = acc[nt][r] + bb;
          if (col < 128) pa[(size_t)row * 128 + col]         = f2bf(v);
          else           pb[(size_t)row * 128 + (col - 128)] = f2bf(v);
        }
      }
    }
  }
}

// ---------------- gather kernel: wave per node, 4-deep scalar-addressed CSR gather ----------------
__global__ __launch_bounds__(256, 8) void k_gather(
    const short* __restrict__ pa, const short* __restrict__ pb,
    const short* __restrict__ tblL,
    const int2* __restrict__ sd_p, const int* __restrict__ colptr,
    short* __restrict__ Sb, int N)
{
  int n = blockIdx.x * 4 + (threadIdx.x >> 6);
  if (n >= N) return;
  const int lane = threadIdx.x & 63;
  const int d2 = lane * 2;

  const int s = colptr[n];
  const int e = colptr[n + 1];

  unsigned up = *(const unsigned*)&pa[(size_t)n * 128 + d2];
  const float p0 = bflo(up), p1 = bfhi(up);
  float s0 = 0.f, s1 = 0.f;

  // per-lane fixed byte offset; per-edge offsets are wave-uniform scalars
  const char* pbB = (const char*)pb + d2 * 2;
  const char* tbB = (const char*)tblL + d2 * 2;

  for (int j = s; j < e; j += 4) {
    unsigned ubv[4], uev[4];
    #pragma unroll
    for (int t = 0; t < 4; ++t) {
      int jj = (j + t < e) ? j + t : s;       // clamp: always a valid record
      int2 r = sd_p[jj];                       // wave-uniform record
      int so = __builtin_amdgcn_readfirstlane(r.x);   // byte offsets -> SGPR
      int to = __builtin_amdgcn_readfirstlane(r.y);
      ubv[t] = *(const unsigned*)(pbB + so);
      uev[t] = *(const unsigned*)(tbB + to);
    }
    #pragma unroll
    for (int t = 0; t < 4; ++t) {
      if (j + t < e) {
        float x0 = p0 + bflo(ubv[t]) + bflo(uev[t]);
        float x1 = p1 + bfhi(ubv[t]) + bfhi(uev[t]);
        s0 += x0 * __builtin_amdgcn_rcpf(1.f + __expf(-x0));
        s1 += x1 * __builtin_amdgcn_rcpf(1.f + __expf(-x1));
      }
    }
  }

  unsigned pk = ((unsigned)(unsigned short)f2bf(s1) << 16) | (unsigned short)f2bf(s0);
  *(unsigned*)&Sb[(size_t)n * 128 + d2] = pk;
}

// ---------------- mean pool (batch_ids sorted): wave per 64 nodes ----------------
__global__ void k_pool(const float* __restrict__ h, const int* __restrict__ batch_ids,
                       float* __restrict__ pooled, float* __restrict__ counts, int N) {
  int lane = threadIdx.x & 63;
  int base = blockIdx.x * 64;
  float acc = 0.f;
  int   cnt = 0;
  int  gcur = -1;
  for (int n = 0; n < 64; ++n) {
    int node = base + n;
    if (node >= N) break;
    int g = batch_ids[node];
    if (g != gcur) {
      if (gcur >= 0) {
        atomicAdd(&pooled[gcur * NODE_DIM + lane], acc);
        if (lane == 0) atomicAdd(&counts[gcur], (float)cnt);
      }
      gcur = g; acc = 0.f; cnt = 0;
    }
    acc += h[(size_t)node * NODE_DIM + lane];
    cnt++;
  }
  if (gcur >= 0) {
    atomicAdd(&pooled[gcur * NODE_DIM + lane], acc);
    if (lane == 0) atomicAdd(&counts[gcur], (float)cnt);
  }
}

__global__ void k_final(const float* __restrict__ pooled, const float* __restrict__ counts,
                        const float* __restrict__ fc_w, const float* __restrict__ fc_b,
                        float* __restrict__ out, int G) {
  int g = blockIdx.x * blockDim.x + threadIdx.x;
  if (g < G) {
    float acc = 0.f;
    for (int d = 0; d < NODE_DIM; ++d) acc += pooled[g * NODE_DIM + d] * fc_w[d];
    float c = counts[g];
    if (c < 1.f) c = 1.f;
    out[g] = acc / c + fc_b[0];
  }
}

extern "C" void kernel_launch(void* const* d_in, const int* in_sizes, int n_in,
                              void* d_out, int out_size, void* d_ws, size_t ws_size,
                              hipStream_t stream) {
  const int*   atoms   = (const int*)  d_in[0];
  const int*   eidx    = (const int*)  d_in[1];
  const float* coords  = (const float*)d_in[2];
  const int*   isr     = (const int*)  d_in[3];
  const int*   batch   = (const int*)  d_in[4];
  const float* embed_w = (const float*)d_in[5];
  const float* sub_w   = (const float*)d_in[6];
  const float* W1      = (const float*)d_in[7];
  const float* b1      = (const float*)d_in[8];
  const float* W2      = (const float*)d_in[9];
  const float* b2      = (const float*)d_in[10];
  const float* fc_w    = (const float*)d_in[11];
  const float* fc_b    = (const float*)d_in[12];
  float* out = (float*)d_out;

  const int N = in_sizes[0];
  const int E = in_sizes[1] / 2;
  const int L = in_sizes[8] / HIDDEN;
  const int G = out_size;

  const int* srcv = eidx;
  const int* dstv = eidx + E;

  size_t off = 0;
  auto carve = [&](size_t bytes) -> char* {
    char* p = (char*)d_ws + off;
    off += (bytes + 255) & ~(size_t)255;
    return p;
  };
  float* hf     = (float*)carve((size_t)N * NODE_DIM * 4);
  short* hb     = (short*)carve((size_t)N * NODE_DIM * 2);
  short* Sb     = (short*)carve((size_t)N * HIDDEN * 2);
  short* pa     = (short*)carve((size_t)N * HIDDEN * 2);
  short* pb     = (short*)carve((size_t)N * HIDDEN * 2);
  int*   ety    = (int*)  carve((size_t)E * 4);
  int*   cnts   = (int*)  carve((size_t)N * 4);
  int*   cursor = (int*)  carve((size_t)N * 4);
  int*   colptr = (int*)  carve(((size_t)N + 2) * 4);
  int2*  sd_p   = (int2*) carve((size_t)E * 8);
  int*   part   = (int*)  carve(((size_t)N / 256 + 2) * 4);
  short* W1abp  = (short*)carve((size_t)L * L1ABSZ * 2);
  short* W2p    = (short*)carve((size_t)L * L2SZ * 2);
  short* tbl    = (short*)carve((size_t)L * TBLSZ * 2);
  float* pooled = (float*)carve((size_t)G * NODE_DIM * 4);
  float* cntg   = (float*)carve((size_t)G * 4);

  const int nbN = (N + 255) / 256;

  k_zero_i<<<nbN, 256, 0, stream>>>(cnts, N);
  k_init<<<1024, 256, 0, stream>>>(atoms, embed_w, hf, hb, N * NODE_DIM);
  k_edge_pre<<<1024, 256, 0, stream>>>(srcv, dstv, coords, isr, ety, cnts, E);
  k_zero_f<<<(G * NODE_DIM + G + 255) / 256, 256, 0, stream>>>(pooled, G * NODE_DIM + G);
  k_scan_part<<<nbN, 256, 0, stream>>>(cnts, part, N);
  k_scan_top<<<1, 512, 0, stream>>>(part, nbN);
  k_scan_apply<<<nbN, 256, 0, stream>>>(cnts, part, cursor, colptr, N, E);
  k_build<<<1024, 256, 0, stream>>>(srcv, dstv, ety, cursor, sd_p, E);
  k_pack_w1ab<<<(L * L1ABSZ + 255) / 256, 256, 0, stream>>>(W1, W1abp, L * L1ABSZ);
  k_pack_w2<<<(L * L2SZ + 255) / 256, 256, 0, stream>>>(W2, W2p, L * L2SZ);
  k_tbl<<<(L * 2 * TBL_BINS + 255) / 256, 256, 0, stream>>>(W1, sub_w, tbl, L * 2 * TBL_BINS);

  const int nblk_n = (N + 63) / 64;
  const int nblk_g = (N + 3) / 4;
  for (int l = 0; l < L; ++l) {
    k_node<<<nblk_n, 256, 0, stream>>>(
        hf, hb, Sb, cnts,
        (l > 0) ? W2p + (size_t)(l - 1) * L2SZ : (const short*)nullptr,
        (l > 0) ? b2 + (size_t)(l - 1) * NODE_DIM : (const float*)nullptr,
        W1abp + (size_t)l * L1ABSZ, b1 + (size_t)l * HIDDEN,
        pa, pb, N);
    k_gather<<<nblk_g, 256, 0, stream>>>(pa, pb, tbl + (size_t)l * TBLSZ,
                                         sd_p, colptr, Sb, N);
  }
  k_node<<<nblk_n, 256, 0, stream>>>(
      hf, hb, Sb, cnts,
      W2p + (size_t)(L - 1) * L2SZ, b2 + (size_t)(L - 1) * NODE_DIM,
      (const short*)nullptr, (const float*)nullptr, pa, pb, N);

  k_pool<<<(N + 63) / 64, 64, 0, stream>>>(hf, batch, pooled, cntg, N);
  k_final<<<1, 64, 0, stream>>>(pooled, cntg, fc_w, fc_b, out, G);
}

// Round 14
// 712.892 us; speedup vs baseline: 1.1749x; 1.0773x over previous
//
#include <hip/hip_runtime.h>
#include <hip/hip_bf16.h>
#include <math.h>

#define NODE_DIM  64
#define EDGE_DIM  32
#define NUM_GAUSS 16
#define HIDDEN    128
#define CAT_DIM   160
#define TBL_BINS  2048
#define TBL_SCALE 256.0f                // bins per unit distance (domain [0,8))
#define L1ABSZ    (64 * 256)            // packed W1ab per layer (K=64, N=256)
#define L2SZ      (HIDDEN * NODE_DIM)   // packed W2 per layer   (K=128, N=64)
#define TBLSZ     (2 * TBL_BINS * 128)  // per-layer edge-attr table entries

// Column-permuted storage: idx64(c)=(c&15)*4+(c>>4)  (64-wide: h, hf, hb, ht)
//                          idx128(c)=(c&15)*8+(c>>4) (128-wide: pa, pb, tbl, Sb)
// Weights' K dims are packed with the same permutation, so all GEMMs are invariant.

typedef __attribute__((ext_vector_type(8))) short short8;
typedef __attribute__((ext_vector_type(4))) short short4v;
typedef __attribute__((ext_vector_type(4))) float float4v;

static __device__ __forceinline__ short f2bf(float x) {
  __hip_bfloat16 h = __float2bfloat16(x);
  return *reinterpret_cast<short*>(&h);
}
static __device__ __forceinline__ float bflo(unsigned u) { return __uint_as_float(u << 16); }
static __device__ __forceinline__ float bfhi(unsigned u) { return __uint_as_float(u & 0xffff0000u); }

// ---------------- init: h (idx64-permuted) = embed[atoms] ----------------
__global__ void k_init(const int* __restrict__ atoms, const float* __restrict__ embed_w,
                       float* __restrict__ hf, short* __restrict__ hb, int n) {
  int stride = gridDim.x * blockDim.x;
  for (int i = blockIdx.x * blockDim.x + threadIdx.x; i < n; i += stride) {
    int p = i & 63;
    int col = (p & 3) * 16 + (p >> 2);          // inverse idx64
    float f = embed_w[atoms[i >> 6] * NODE_DIM + col];
    hf[i] = f;
    hb[i] = f2bf(f);
  }
}

__global__ void k_zero_f(float* __restrict__ p, int n) {
  int stride = gridDim.x * blockDim.x;
  for (int i = blockIdx.x * blockDim.x + threadIdx.x; i < n; i += stride) p[i] = 0.f;
}
__global__ void k_zero_i(int* __restrict__ p, int n) {
  int i = blockIdx.x * blockDim.x + threadIdx.x;
  if (i < n) p[i] = 0;
}

// ---------------- edge precompute: ety = (kind<<11) | bin(dist); fused dst histogram ----------------
__global__ void k_edge_pre(const int* __restrict__ src, const int* __restrict__ dst,
                           const float* __restrict__ coords, const int* __restrict__ isr,
                           int* __restrict__ ety, int* __restrict__ counts, int E) {
  int stride = gridDim.x * blockDim.x;
  for (int e = blockIdx.x * blockDim.x + threadIdx.x; e < E; e += stride) {
    int s = src[e], d = dst[e];
    float dx = coords[s*3+0] - coords[d*3+0];
    float dy = coords[s*3+1] - coords[d*3+1];
    float dz = coords[s*3+2] - coords[d*3+2];
    float dist = sqrtf(dx*dx + dy*dy + dz*dz);
    int bin = (int)(dist * TBL_SCALE);
    bin = (bin > TBL_BINS - 1) ? TBL_BINS - 1 : bin;
    int kind = (isr[s] != isr[d]) ? 1 : 0;
    ety[e] = (kind << 11) | bin;
    atomicAdd(&counts[d], 1);
  }
}

// ---------------- edge-attr table (idx128-permuted cols) ----------------
__global__ void k_tbl(const float* __restrict__ W1, const float* __restrict__ sub_w,
                      short* __restrict__ tbl, int total) {
  int idx = blockIdx.x * 256 + threadIdx.x;   // thread per (l, kind, bin)
  if (idx >= total) return;
  int bin  = idx & (TBL_BINS - 1);
  int kind = (idx >> 11) & 1;
  int l    = idx >> 12;
  float dist = ((float)bin + 0.5f) * (1.0f / TBL_SCALE);
  float rbf[16], skv[16];
  #pragma unroll
  for (int g = 0; g < 16; ++g) {
    float t = dist - (float)g * (1.0f / 3.0f);
    rbf[g] = __expf(-4.5f * t * t);
    skv[g] = sub_w[kind * 16 + g];
  }
  const float* W1c = W1 + (size_t)l * CAT_DIM * HIDDEN + 128 * HIDDEN;
  short* outp = tbl + ((size_t)idx) * 128;
  #pragma unroll 4
  for (int col = 0; col < 128; ++col) {
    float acc = 0.f;
    #pragma unroll
    for (int g = 0; g < 16; ++g) acc += rbf[g] * W1c[g * 128 + col];
    #pragma unroll
    for (int g = 0; g < 16; ++g) acc += skv[g] * W1c[(16 + g) * 128 + col];
    outp[(col & 15) * 8 + (col >> 4)] = f2bf(acc);   // idx128
  }
}

// ---------------- CSR build ----------------
__global__ void k_scan_part(const int* __restrict__ counts, int* __restrict__ part, int N) {
  __shared__ int red[256];
  int t = threadIdx.x;
  int i = blockIdx.x * 256 + t;
  red[t] = (i < N) ? counts[i] : 0;
  __syncthreads();
  for (int o = 128; o > 0; o >>= 1) {
    if (t < o) red[t] += red[t + o];
    __syncthreads();
  }
  if (t == 0) part[blockIdx.x] = red[0];
}

__global__ void k_scan_top(int* __restrict__ part, int nb) {
  __shared__ int s[512];
  int t = threadIdx.x;
  int v = (t < nb) ? part[t] : 0;
  s[t] = v;
  __syncthreads();
  for (int o = 1; o < 512; o <<= 1) {
    int u = (t >= o) ? s[t - o] : 0;
    __syncthreads();
    s[t] += u;
    __syncthreads();
  }
  if (t < nb) part[t] = s[t] - v;   // exclusive
}

__global__ void k_scan_apply(const int* __restrict__ counts, const int* __restrict__ part,
                             int* __restrict__ cursor, int* __restrict__ colptr,
                             int N, int E) {
  __shared__ int s[256];
  int t = threadIdx.x;
  int i = blockIdx.x * 256 + t;
  int v = (i < N) ? counts[i] : 0;
  s[t] = v;
  __syncthreads();
  for (int o = 1; o < 256; o <<= 1) {
    int u = (t >= o) ? s[t - o] : 0;
    __syncthreads();
    s[t] += u;
    __syncthreads();
  }
  if (i < N) {
    int ex = part[blockIdx.x] + s[t] - v;   // exclusive prefix
    cursor[i] = ex;
    colptr[i] = ex;
    if (i == N - 1) colptr[N] = E;
  }
}

// scatter (src*256, ety*256) BYTE OFFSETS into dst-sorted order
__global__ void k_build(const int* __restrict__ src, const int* __restrict__ dst,
                        const int* __restrict__ ety, int* __restrict__ cursor,
                        int2* __restrict__ sd_p, int E) {
  int stride = gridDim.x * blockDim.x;
  for (int e = blockIdx.x * blockDim.x + threadIdx.x; e < E; e += stride) {
    int d = dst[e];
    int p = atomicAdd(&cursor[d], 1);
    sd_p[p] = make_int2(src[e] << 8, ety[e] << 8);   // 256 B per row
  }
}

// ---------------- weight packing: B-frag order, K permuted to match storage ----------------
__global__ void k_pack_w1ab(const float* __restrict__ W1, short* __restrict__ Wp, int total) {
  int i = blockIdx.x * blockDim.x + threadIdx.x;
  if (i >= total) return;
  int l = i / L1ABSZ, r = i % L1ABSZ;
  int k = r / 256, n = r % 256;                 // k = original h col (0..63)
  int kp = (k & 15) * 4 + (k >> 4);             // idx64
  int kt = kp >> 5, quad = (kp >> 3) & 3, j = kp & 7;
  int srow = (n < 128) ? k : 64 + k;
  int scol = (n < 128) ? n : n - 128;
  Wp[l * L1ABSZ + ((kt*4 + quad) * 256 + n) * 8 + j] =
      f2bf(W1[(size_t)l * CAT_DIM * HIDDEN + srow * HIDDEN + scol]);
}
__global__ void k_pack_w2(const float* __restrict__ W, short* __restrict__ Wp, int total) {
  int i = blockIdx.x * blockDim.x + threadIdx.x;
  if (i >= total) return;
  int l = i / L2SZ, r = i % L2SZ;
  int k = r / NODE_DIM, n = r % NODE_DIM;       // k = original hidden col (0..127)
  int kp = (k & 15) * 8 + (k >> 4);             // idx128
  int kt = kp >> 5, quad = (kp >> 3) & 3, j = kp & 7;
  Wp[l * L2SZ + ((kt*4 + quad) * NODE_DIM + n) * 8 + j] = f2bf(W[i]);
}

// ---------------- node kernel: [agg=Sb@W2+cnt*b2; h=relu(h+agg)] ; [pa|pb = h@W1ab] ----------------
__global__ __launch_bounds__(256, 4) void k_node(
    float* __restrict__ hf, const short* __restrict__ hb,
    const short* __restrict__ Sb, const int* __restrict__ cnts,
    const short* __restrict__ W2p, const float* __restrict__ b2,
    const short* __restrict__ W1abp, const float* __restrict__ b1,
    short* __restrict__ pa, short* __restrict__ pb, int N)
{
  __shared__ short ht[64 * 72];

  const int tid  = threadIdx.x;
  const int lane = tid & 63;
  const int w    = tid >> 6;
  const int quad = lane >> 4;
  const int l16  = lane & 15;
  const int base = blockIdx.x * 64 + w * 16;

  if (W2p) {
    float4v acc[4];
    #pragma unroll
    for (int nt = 0; nt < 4; ++nt) acc[nt] = (float4v)0.f;
    const int arow = base + l16;
    const bool av = arow < N;
    #pragma unroll
    for (int kt = 0; kt < 4; ++kt) {
      short8 a = av ? *(const short8*)&Sb[(size_t)arow * 128 + kt*32 + quad*8]
                    : (short8)0;
      #pragma unroll
      for (int nt = 0; nt < 4; ++nt) {
        short8 b = *(const short8*)&W2p[((kt*4 + quad) * NODE_DIM + nt*16 + l16) * 8];
        acc[nt] = __builtin_amdgcn_mfma_f32_16x16x32_bf16(a, b, acc[nt], 0, 0, 0);
      }
    }
    float bb[4];
    #pragma unroll
    for (int nt = 0; nt < 4; ++nt) bb[nt] = b2[nt*16 + l16];
    #pragma unroll
    for (int r = 0; r < 4; ++r) {
      int row  = base + quad*4 + r;
      int lrow = w*16 + quad*4 + r;
      if (row < N) {
        float cf = (float)cnts[row];
        float4 hv = *(const float4*)&hf[(size_t)row * 64 + l16*4];   // permuted pos l16*4+nt
        float v0 = fmaxf(hv.x + acc[0][r] + cf * bb[0], 0.f);
        float v1 = fmaxf(hv.y + acc[1][r] + cf * bb[1], 0.f);
        float v2 = fmaxf(hv.z + acc[2][r] + cf * bb[2], 0.f);
        float v3 = fmaxf(hv.w + acc[3][r] + cf * bb[3], 0.f);
        *(float4*)&hf[(size_t)row * 64 + l16*4] = make_float4(v0, v1, v2, v3);
        short4v hs = {f2bf(v0), f2bf(v1), f2bf(v2), f2bf(v3)};
        *(short4v*)&ht[lrow * 72 + l16*4] = hs;
      } else {
        *(short4v*)&ht[lrow * 72 + l16*4] = (short4v)0;
      }
    }
  } else {
    int row = base + l16;
    #pragma unroll
    for (int c = 0; c < 2; ++c) {
      int colc = quad*16 + c*8;
      short8 v = (row < N) ? *(const short8*)&hb[(size_t)row * 64 + colc] : (short8)0;
      *(short8*)&ht[(w*16 + l16) * 72 + colc] = v;
    }
  }

  if (W1abp) {
    float4v acc[16];
    #pragma unroll
    for (int nt = 0; nt < 16; ++nt) acc[nt] = (float4v)0.f;
    #pragma unroll
    for (int kt = 0; kt < 2; ++kt) {
      short8 a = *(const short8*)&ht[(w*16 + l16) * 72 + kt*32 + quad*8];
      #pragma unroll
      for (int nt = 0; nt < 16; ++nt) {
        short8 b = *(const short8*)&W1abp[((kt*4 + quad) * 256 + nt*16 + l16) * 8];
        acc[nt] = __builtin_amdgcn_mfma_f32_16x16x32_bf16(a, b, acc[nt], 0, 0, 0);
      }
    }
    float b1a[8];
    #pragma unroll
    for (int nt = 0; nt < 8; ++nt) b1a[nt] = b1[nt*16 + l16];
    #pragma unroll
    for (int r = 0; r < 4; ++r) {
      int row = base + quad*4 + r;
      if (row < N) {
        short8 va, vb;
        #pragma unroll
        for (int nt = 0; nt < 8; ++nt) va[nt] = f2bf(acc[nt][r] + b1a[nt]);
        #pragma unroll
        for (int nt = 0; nt < 8; ++nt) vb[nt] = f2bf(acc[nt + 8][r]);
        *(short8*)&pa[(size_t)row * 128 + l16*8] = va;   // permuted pos l16*8+nt
        *(short8*)&pb[(size_t)row * 128 + l16*8] = vb;
      }
    }
  }
}

// ---------------- gather kernel: wave per node, 4-deep double-buffered CSR gather ----------------
__global__ __launch_bounds__(256, 8) void k_gather(
    const short* __restrict__ pa, const short* __restrict__ pb,
    const short* __restrict__ tblL,
    const int2* __restrict__ sd_p, const int* __restrict__ colptr,
    short* __restrict__ Sb, int N)
{
  int n = blockIdx.x * 4 + (threadIdx.x >> 6);
  if (n >= N) return;
  const int lane = threadIdx.x & 63;
  const int d2 = lane * 2;

  const int s = colptr[n];
  const int e = colptr[n + 1];

  unsigned up = *(const unsigned*)&pa[(size_t)n * 128 + d2];
  const float p0 = bflo(up), p1 = bfhi(up);
  float s0 = 0.f, s1 = 0.f;

  const char* pbB = (const char*)pb + d2 * 2;
  const char* tbB = (const char*)tblL + d2 * 2;

  if (e > s) {
    unsigned ub0[4], ue0[4], ub1[4], ue1[4];

    auto load4 = [&](unsigned (&ub)[4], unsigned (&ue)[4], int j) {
      #pragma unroll
      for (int t = 0; t < 4; ++t) {
        int jj = (j + t < e) ? j + t : s;       // clamp: always a valid record
        int2 r = sd_p[jj];                       // wave-uniform record
        int so = __builtin_amdgcn_readfirstlane(r.x);   // byte offsets -> SGPR
        int to = __builtin_amdgcn_readfirstlane(r.y);
        ub[t] = *(const unsigned*)(pbB + so);
        ue[t] = *(const unsigned*)(tbB + to);
      }
    };
    auto consume4 = [&](unsigned (&ub)[4], unsigned (&ue)[4], int j) {
      #pragma unroll
      for (int t = 0; t < 4; ++t) {
        if (j + t < e) {
          float x0 = p0 + bflo(ub[t]) + bflo(ue[t]);
          float x1 = p1 + bfhi(ub[t]) + bfhi(ue[t]);
          s0 += x0 * __builtin_amdgcn_rcpf(1.f + __expf(-x0));
          s1 += x1 * __builtin_amdgcn_rcpf(1.f + __expf(-x1));
        }
      }
    };

    load4(ub0, ue0, s);
    int j = s;
    for (; j + 4 < e; j += 8) {
      load4(ub1, ue1, j + 4);
      consume4(ub0, ue0, j);
      if (j + 8 < e) load4(ub0, ue0, j + 8);
      consume4(ub1, ue1, j + 4);
    }
    if (j < e) consume4(ub0, ue0, j);
  }

  unsigned pk = ((unsigned)(unsigned short)f2bf(s1) << 16) | (unsigned short)f2bf(s0);
  *(unsigned*)&Sb[(size_t)n * 128 + d2] = pk;
}

// ---------------- mean pool (batch_ids sorted): wave per 64 nodes ----------------
__global__ void k_pool(const float* __restrict__ h, const int* __restrict__ batch_ids,
                       float* __restrict__ pooled, float* __restrict__ counts, int N) {
  int lane = threadIdx.x & 63;
  int base = blockIdx.x * 64;
  float acc = 0.f;
  int   cnt = 0;
  int  gcur = -1;
  for (int n = 0; n < 64; ++n) {
    int node = base + n;
    if (node >= N) break;
    int g = batch_ids[node];
    if (g != gcur) {
      if (gcur >= 0) {
        atomicAdd(&pooled[gcur * NODE_DIM + lane], acc);
        if (lane == 0) atomicAdd(&counts[gcur], (float)cnt);
      }
      gcur = g; acc = 0.f; cnt = 0;
    }
    acc += h[(size_t)node * NODE_DIM + lane];
    cnt++;
  }
  if (gcur >= 0) {
    atomicAdd(&pooled[gcur * NODE_DIM + lane], acc);
    if (lane == 0) atomicAdd(&counts[gcur], (float)cnt);
  }
}

// final linear: un-permute fc_w (pooled is idx64-permuted)
__global__ void k_final(const float* __restrict__ pooled, const float* __restrict__ counts,
                        const float* __restrict__ fc_w, const float* __restrict__ fc_b,
                        float* __restrict__ out, int G) {
  int g = blockIdx.x * blockDim.x + threadIdx.x;
  if (g < G) {
    float acc = 0.f;
    for (int d = 0; d < NODE_DIM; ++d) {
      int col = (d & 3) * 16 + (d >> 2);      // inverse idx64
      acc += pooled[g * NODE_DIM + d] * fc_w[col];
    }
    float c = counts[g];
    if (c < 1.f) c = 1.f;
    out[g] = acc / c + fc_b[0];
  }
}

extern "C" void kernel_launch(void* const* d_in, const int* in_sizes, int n_in,
                              void* d_out, int out_size, void* d_ws, size_t ws_size,
                              hipStream_t stream) {
  const int*   atoms   = (const int*)  d_in[0];
  const int*   eidx    = (const int*)  d_in[1];
  const float* coords  = (const float*)d_in[2];
  const int*   isr     = (const int*)  d_in[3];
  const int*   batch   = (const int*)  d_in[4];
  const float* embed_w = (const float*)d_in[5];
  const float* sub_w   = (const float*)d_in[6];
  const float* W1      = (const float*)d_in[7];
  const float* b1      = (const float*)d_in[8];
  const float* W2      = (const float*)d_in[9];
  const float* b2      = (const float*)d_in[10];
  const float* fc_w    = (const float*)d_in[11];
  const float* fc_b    = (const float*)d_in[12];
  float* out = (float*)d_out;

  const int N = in_sizes[0];
  const int E = in_sizes[1] / 2;
  const int L = in_sizes[8] / HIDDEN;
  const int G = out_size;

  const int* srcv = eidx;
  const int* dstv = eidx + E;

  size_t off = 0;
  auto carve = [&](size_t bytes) -> char* {
    char* p = (char*)d_ws + off;
    off += (bytes + 255) & ~(size_t)255;
    return p;
  };
  float* hf     = (float*)carve((size_t)N * NODE_DIM * 4);
  short* hb     = (short*)carve((size_t)N * NODE_DIM * 2);
  short* Sb     = (short*)carve((size_t)N * HIDDEN * 2);
  short* pa     = (short*)carve((size_t)N * HIDDEN * 2);
  short* pb     = (short*)carve((size_t)N * HIDDEN * 2);
  int*   ety    = (int*)  carve((size_t)E * 4);
  int*   cnts   = (int*)  carve((size_t)N * 4);
  int*   cursor = (int*)  carve((size_t)N * 4);
  int*   colptr = (int*)  carve(((size_t)N + 2) * 4);
  int2*  sd_p   = (int2*) carve((size_t)E * 8);
  int*   part   = (int*)  carve(((size_t)N / 256 + 2) * 4);
  short* W1abp  = (short*)carve((size_t)L * L1ABSZ * 2);
  short* W2p    = (short*)carve((size_t)L * L2SZ * 2);
  short* tbl    = (short*)carve((size_t)L * TBLSZ * 2);
  float* pooled = (float*)carve((size_t)G * NODE_DIM * 4);
  float* cntg   = (float*)carve((size_t)G * 4);

  const int nbN = (N + 255) / 256;

  k_zero_i<<<nbN, 256, 0, stream>>>(cnts, N);
  k_init<<<1024, 256, 0, stream>>>(atoms, embed_w, hf, hb, N * NODE_DIM);
  k_edge_pre<<<1024, 256, 0, stream>>>(srcv, dstv, coords, isr, ety, cnts, E);
  k_zero_f<<<(G * NODE_DIM + G + 255) / 256, 256, 0, stream>>>(pooled, G * NODE_DIM + G);
  k_scan_part<<<nbN, 256, 0, stream>>>(cnts, part, N);
  k_scan_top<<<1, 512, 0, stream>>>(part, nbN);
  k_scan_apply<<<nbN, 256, 0, stream>>>(cnts, part, cursor, colptr, N, E);
  k_build<<<1024, 256, 0, stream>>>(srcv, dstv, ety, cursor, sd_p, E);
  k_pack_w1ab<<<(L * L1ABSZ + 255) / 256, 256, 0, stream>>>(W1, W1abp, L * L1ABSZ);
  k_pack_w2<<<(L * L2SZ + 255) / 256, 256, 0, stream>>>(W2, W2p, L * L2SZ);
  k_tbl<<<(L * 2 * TBL_BINS + 255) / 256, 256, 0, stream>>>(W1, sub_w, tbl, L * 2 * TBL_BINS);

  const int nblk_n = (N + 63) / 64;
  const int nblk_g = (N + 3) / 4;
  for (int l = 0; l < L; ++l) {
    k_node<<<nblk_n, 256, 0, stream>>>(
        hf, hb, Sb, cnts,
        (l > 0) ? W2p + (size_t)(l - 1) * L2SZ : (const short*)nullptr,
        (l > 0) ? b2 + (size_t)(l - 1) * NODE_DIM : (const float*)nullptr,
        W1abp + (size_t)l * L1ABSZ, b1 + (size_t)l * HIDDEN,
        pa, pb, N);
    k_gather<<<nblk_g, 256, 0, stream>>>(pa, pb, tbl + (size_t)l * TBLSZ,
                                         sd_p, colptr, Sb, N);
  }
  k_node<<<nblk_n, 256, 0, stream>>>(
      hf, hb, Sb, cnts,
      W2p + (size_t)(L - 1) * L2SZ, b2 + (size_t)(L - 1) * NODE_DIM,
      (const short*)nullptr, (const float*)nullptr, pa, pb, N);

  k_pool<<<(N + 63) / 64, 64, 0, stream>>>(hf, batch, pooled, cntg, N);
  k_final<<<1, 64, 0, stream>>>(pooled, cntg, fc_w, fc_b, out, G);
}

// Round 15
// 691.736 us; speedup vs baseline: 1.2108x; 1.0306x over previous
//
#include <hip/hip_runtime.h>
#include <hip/hip_bf16.h>
#include <math.h>

#define NODE_DIM  64
#define EDGE_DIM  32
#define NUM_GAUSS 16
#define HIDDEN    128
#define CAT_DIM   160
#define TBL_BINS  2048
#define TBL_SCALE 256.0f                // bins per unit distance (domain [0,8))
#define L1ABSZ    (64 * 256)            // packed W1ab per layer (K=64, N=256)
#define L2SZ      (HIDDEN * NODE_DIM)   // packed W2 per layer   (K=128, N=64)
#define TBLSZ     (2 * TBL_BINS * 128)  // per-layer edge-attr table entries

// Column-permuted storage: idx64(c)=(c&15)*4+(c>>4)  (64-wide: h, hf, hb, ht)
//                          idx128(c)=(c&15)*8+(c>>4) (128-wide: pa, pb, tbl, Sb)
// Weights' K dims are packed with the same permutation, so all GEMMs are invariant.
// Edge record: rec = (src << 12) | ety   (src<2^20, ety<2^12) — single 4 B scatter.

typedef __attribute__((ext_vector_type(8))) short short8;
typedef __attribute__((ext_vector_type(4))) short short4v;
typedef __attribute__((ext_vector_type(4))) float float4v;

static __device__ __forceinline__ short f2bf(float x) {
  __hip_bfloat16 h = __float2bfloat16(x);
  return *reinterpret_cast<short*>(&h);
}
static __device__ __forceinline__ float bflo(unsigned u) { return __uint_as_float(u << 16); }
static __device__ __forceinline__ float bfhi(unsigned u) { return __uint_as_float(u & 0xffff0000u); }

// ---------------- init: h (idx64-permuted) = embed[atoms] ----------------
__global__ void k_init(const int* __restrict__ atoms, const float* __restrict__ embed_w,
                       float* __restrict__ hf, short* __restrict__ hb, int n) {
  int stride = gridDim.x * blockDim.x;
  for (int i = blockIdx.x * blockDim.x + threadIdx.x; i < n; i += stride) {
    int p = i & 63;
    int col = (p & 3) * 16 + (p >> 2);          // inverse idx64
    float f = embed_w[atoms[i >> 6] * NODE_DIM + col];
    hf[i] = f;
    hb[i] = f2bf(f);
  }
}

__global__ void k_zero_f(float* __restrict__ p, int n) {
  int stride = gridDim.x * blockDim.x;
  for (int i = blockIdx.x * blockDim.x + threadIdx.x; i < n; i += stride) p[i] = 0.f;
}
__global__ void k_zero_i(int* __restrict__ p, int n) {
  int i = blockIdx.x * blockDim.x + threadIdx.x;
  if (i < n) p[i] = 0;
}

// ---------------- edge precompute: ety = (kind<<11) | bin(dist); fused dst histogram ----------------
__global__ void k_edge_pre(const int* __restrict__ src, const int* __restrict__ dst,
                           const float* __restrict__ coords, const int* __restrict__ isr,
                           int* __restrict__ ety, int* __restrict__ counts, int E) {
  int stride = gridDim.x * blockDim.x;
  for (int e = blockIdx.x * blockDim.x + threadIdx.x; e < E; e += stride) {
    int s = src[e], d = dst[e];
    float dx = coords[s*3+0] - coords[d*3+0];
    float dy = coords[s*3+1] - coords[d*3+1];
    float dz = coords[s*3+2] - coords[d*3+2];
    float dist = sqrtf(dx*dx + dy*dy + dz*dz);
    int bin = (int)(dist * TBL_SCALE);
    bin = (bin > TBL_BINS - 1) ? TBL_BINS - 1 : bin;
    int kind = (isr[s] != isr[d]) ? 1 : 0;
    ety[e] = (kind << 11) | bin;
    atomicAdd(&counts[d], 1);
  }
}

// ---------------- edge-attr table (idx128-permuted cols) ----------------
__global__ void k_tbl(const float* __restrict__ W1, const float* __restrict__ sub_w,
                      short* __restrict__ tbl, int total) {
  int idx = blockIdx.x * 256 + threadIdx.x;   // thread per (l, kind, bin)
  if (idx >= total) return;
  int bin  = idx & (TBL_BINS - 1);
  int kind = (idx >> 11) & 1;
  int l    = idx >> 12;
  float dist = ((float)bin + 0.5f) * (1.0f / TBL_SCALE);
  float rbf[16], skv[16];
  #pragma unroll
  for (int g = 0; g < 16; ++g) {
    float t = dist - (float)g * (1.0f / 3.0f);
    rbf[g] = __expf(-4.5f * t * t);
    skv[g] = sub_w[kind * 16 + g];
  }
  const float* W1c = W1 + (size_t)l * CAT_DIM * HIDDEN + 128 * HIDDEN;
  short* outp = tbl + ((size_t)idx) * 128;
  #pragma unroll 4
  for (int col = 0; col < 128; ++col) {
    float acc = 0.f;
    #pragma unroll
    for (int g = 0; g < 16; ++g) acc += rbf[g] * W1c[g * 128 + col];
    #pragma unroll
    for (int g = 0; g < 16; ++g) acc += skv[g] * W1c[(16 + g) * 128 + col];
    outp[(col & 15) * 8 + (col >> 4)] = f2bf(acc);   // idx128
  }
}

// ---------------- CSR build ----------------
__global__ void k_scan_part(const int* __restrict__ counts, int* __restrict__ part, int N) {
  __shared__ int red[256];
  int t = threadIdx.x;
  int i = blockIdx.x * 256 + t;
  red[t] = (i < N) ? counts[i] : 0;
  __syncthreads();
  for (int o = 128; o > 0; o >>= 1) {
    if (t < o) red[t] += red[t + o];
    __syncthreads();
  }
  if (t == 0) part[blockIdx.x] = red[0];
}

__global__ void k_scan_top(int* __restrict__ part, int nb) {
  __shared__ int s[512];
  int t = threadIdx.x;
  int v = (t < nb) ? part[t] : 0;
  s[t] = v;
  __syncthreads();
  for (int o = 1; o < 512; o <<= 1) {
    int u = (t >= o) ? s[t - o] : 0;
    __syncthreads();
    s[t] += u;
    __syncthreads();
  }
  if (t < nb) part[t] = s[t] - v;   // exclusive
}

__global__ void k_scan_apply(const int* __restrict__ counts, const int* __restrict__ part,
                             int* __restrict__ cursor, int* __restrict__ colptr,
                             int N, int E) {
  __shared__ int s[256];
  int t = threadIdx.x;
  int i = blockIdx.x * 256 + t;
  int v = (i < N) ? counts[i] : 0;
  s[t] = v;
  __syncthreads();
  for (int o = 1; o < 256; o <<= 1) {
    int u = (t >= o) ? s[t - o] : 0;
    __syncthreads();
    s[t] += u;
    __syncthreads();
  }
  if (i < N) {
    int ex = part[blockIdx.x] + s[t] - v;   // exclusive prefix
    cursor[i] = ex;
    colptr[i] = ex;
    if (i == N - 1) colptr[N] = E;
  }
}

// scatter packed (src<<12 | ety) records into dst-sorted order (4 B stores)
__global__ void k_build(const int* __restrict__ src, const int* __restrict__ dst,
                        const int* __restrict__ ety, int* __restrict__ cursor,
                        int* __restrict__ sd_p, int E) {
  int stride = gridDim.x * blockDim.x;
  for (int e = blockIdx.x * blockDim.x + threadIdx.x; e < E; e += stride) {
    int d = dst[e];
    int p = atomicAdd(&cursor[d], 1);
    sd_p[p] = (src[e] << 12) | ety[e];
  }
}

// ---------------- weight packing: B-frag order, K permuted to match storage ----------------
__global__ void k_pack_w1ab(const float* __restrict__ W1, short* __restrict__ Wp, int total) {
  int i = blockIdx.x * blockDim.x + threadIdx.x;
  if (i >= total) return;
  int l = i / L1ABSZ, r = i % L1ABSZ;
  int k = r / 256, n = r % 256;                 // k = original h col (0..63)
  int kp = (k & 15) * 4 + (k >> 4);             // idx64
  int kt = kp >> 5, quad = (kp >> 3) & 3, j = kp & 7;
  int srow = (n < 128) ? k : 64 + k;
  int scol = (n < 128) ? n : n - 128;
  Wp[l * L1ABSZ + ((kt*4 + quad) * 256 + n) * 8 + j] =
      f2bf(W1[(size_t)l * CAT_DIM * HIDDEN + srow * HIDDEN + scol]);
}
__global__ void k_pack_w2(const float* __restrict__ W, short* __restrict__ Wp, int total) {
  int i = blockIdx.x * blockDim.x + threadIdx.x;
  if (i >= total) return;
  int l = i / L2SZ, r = i % L2SZ;
  int k = r / NODE_DIM, n = r % NODE_DIM;       // k = original hidden col (0..127)
  int kp = (k & 15) * 8 + (k >> 4);             // idx128
  int kt = kp >> 5, quad = (kp >> 3) & 3, j = kp & 7;
  Wp[l * L2SZ + ((kt*4 + quad) * NODE_DIM + n) * 8 + j] = f2bf(W[i]);
}

// ---------------- node kernel: [agg=Sb@W2+cnt*b2; h=relu(h+agg)] ; [pa|pb = h@W1ab] ----------------
__global__ __launch_bounds__(256, 4) void k_node(
    float* __restrict__ hf, const short* __restrict__ hb,
    const short* __restrict__ Sb, const int* __restrict__ cnts,
    const short* __restrict__ W2p, const float* __restrict__ b2,
    const short* __restrict__ W1abp, const float* __restrict__ b1,
    short* __restrict__ pa, short* __restrict__ pb, int N)
{
  __shared__ short ht[64 * 72];

  const int tid  = threadIdx.x;
  const int lane = tid & 63;
  const int w    = tid >> 6;
  const int quad = lane >> 4;
  const int l16  = lane & 15;
  const int base = blockIdx.x * 64 + w * 16;

  if (W2p) {
    float4v acc[4];
    #pragma unroll
    for (int nt = 0; nt < 4; ++nt) acc[nt] = (float4v)0.f;
    const int arow = base + l16;
    const bool av = arow < N;
    #pragma unroll
    for (int kt = 0; kt < 4; ++kt) {
      short8 a = av ? *(const short8*)&Sb[(size_t)arow * 128 + kt*32 + quad*8]
                    : (short8)0;
      #pragma unroll
      for (int nt = 0; nt < 4; ++nt) {
        short8 b = *(const short8*)&W2p[((kt*4 + quad) * NODE_DIM + nt*16 + l16) * 8];
        acc[nt] = __builtin_amdgcn_mfma_f32_16x16x32_bf16(a, b, acc[nt], 0, 0, 0);
      }
    }
    float bb[4];
    #pragma unroll
    for (int nt = 0; nt < 4; ++nt) bb[nt] = b2[nt*16 + l16];
    #pragma unroll
    for (int r = 0; r < 4; ++r) {
      int row  = base + quad*4 + r;
      int lrow = w*16 + quad*4 + r;
      if (row < N) {
        float cf = (float)cnts[row];
        float4 hv = *(const float4*)&hf[(size_t)row * 64 + l16*4];   // permuted pos l16*4+nt
        float v0 = fmaxf(hv.x + acc[0][r] + cf * bb[0], 0.f);
        float v1 = fmaxf(hv.y + acc[1][r] + cf * bb[1], 0.f);
        float v2 = fmaxf(hv.z + acc[2][r] + cf * bb[2], 0.f);
        float v3 = fmaxf(hv.w + acc[3][r] + cf * bb[3], 0.f);
        *(float4*)&hf[(size_t)row * 64 + l16*4] = make_float4(v0, v1, v2, v3);
        short4v hs = {f2bf(v0), f2bf(v1), f2bf(v2), f2bf(v3)};
        *(short4v*)&ht[lrow * 72 + l16*4] = hs;
      } else {
        *(short4v*)&ht[lrow * 72 + l16*4] = (short4v)0;
      }
    }
  } else {
    int row = base + l16;
    #pragma unroll
    for (int c = 0; c < 2; ++c) {
      int colc = quad*16 + c*8;
      short8 v = (row < N) ? *(const short8*)&hb[(size_t)row * 64 + colc] : (short8)0;
      *(short8*)&ht[(w*16 + l16) * 72 + colc] = v;
    }
  }

  if (W1abp) {
    float4v acc[16];
    #pragma unroll
    for (int nt = 0; nt < 16; ++nt) acc[nt] = (float4v)0.f;
    #pragma unroll
    for (int kt = 0; kt < 2; ++kt) {
      short8 a = *(const short8*)&ht[(w*16 + l16) * 72 + kt*32 + quad*8];
      #pragma unroll
      for (int nt = 0; nt < 16; ++nt) {
        short8 b = *(const short8*)&W1abp[((kt*4 + quad) * 256 + nt*16 + l16) * 8];
        acc[nt] = __builtin_amdgcn_mfma_f32_16x16x32_bf16(a, b, acc[nt], 0, 0, 0);
      }
    }
    float b1a[8];
    #pragma unroll
    for (int nt = 0; nt < 8; ++nt) b1a[nt] = b1[nt*16 + l16];
    #pragma unroll
    for (int r = 0; r < 4; ++r) {
      int row = base + quad*4 + r;
      if (row < N) {
        short8 va, vb;
        #pragma unroll
        for (int nt = 0; nt < 8; ++nt) va[nt] = f2bf(acc[nt][r] + b1a[nt]);
        #pragma unroll
        for (int nt = 0; nt < 8; ++nt) vb[nt] = f2bf(acc[nt + 8][r]);
        *(short8*)&pa[(size_t)row * 128 + l16*8] = va;   // permuted pos l16*8+nt
        *(short8*)&pb[(size_t)row * 128 + l16*8] = vb;
      }
    }
  }
}

// ---------------- gather kernel: wave per node, 4-deep double-buffered CSR gather ----------------
__global__ __launch_bounds__(256, 8) void k_gather(
    const short* __restrict__ pa, const short* __restrict__ pb,
    const short* __restrict__ tblL,
    const int* __restrict__ sd_p, const int* __restrict__ colptr,
    short* __restrict__ Sb, int N)
{
  int n = blockIdx.x * 4 + (threadIdx.x >> 6);
  if (n >= N) return;
  const int lane = threadIdx.x & 63;
  const int d2 = lane * 2;

  const int s = colptr[n];
  const int e = colptr[n + 1];

  unsigned up = *(const unsigned*)&pa[(size_t)n * 128 + d2];
  const float p0 = bflo(up), p1 = bfhi(up);
  float s0 = 0.f, s1 = 0.f;

  const char* pbB = (const char*)pb + d2 * 2;
  const char* tbB = (const char*)tblL + d2 * 2;

  if (e > s) {
    unsigned ub0[4], ue0[4], ub1[4], ue1[4];

    auto load4 = [&](unsigned (&ub)[4], unsigned (&ue)[4], int j) {
      #pragma unroll
      for (int t = 0; t < 4; ++t) {
        int jj = (j + t < e) ? j + t : s;       // clamp: always a valid record
        int rc = __builtin_amdgcn_readfirstlane(sd_p[jj]);  // wave-uniform scalar
        int so = (rc >> 12) << 8;               // src byte offset (256 B rows)
        int to = (rc & 0xfff) << 8;             // ety byte offset
        ub[t] = *(const unsigned*)(pbB + so);
        ue[t] = *(const unsigned*)(tbB + to);
      }
    };
    auto consume4 = [&](unsigned (&ub)[4], unsigned (&ue)[4], int j) {
      #pragma unroll
      for (int t = 0; t < 4; ++t) {
        if (j + t < e) {
          float x0 = p0 + bflo(ub[t]) + bflo(ue[t]);
          float x1 = p1 + bfhi(ub[t]) + bfhi(ue[t]);
          s0 += x0 * __builtin_amdgcn_rcpf(1.f + __expf(-x0));
          s1 += x1 * __builtin_amdgcn_rcpf(1.f + __expf(-x1));
        }
      }
    };

    load4(ub0, ue0, s);
    int j = s;
    for (; j + 4 < e; j += 8) {
      load4(ub1, ue1, j + 4);
      consume4(ub0, ue0, j);
      if (j + 8 < e) load4(ub0, ue0, j + 8);
      consume4(ub1, ue1, j + 4);
    }
    if (j < e) consume4(ub0, ue0, j);
  }

  unsigned pk = ((unsigned)(unsigned short)f2bf(s1) << 16) | (unsigned short)f2bf(s0);
  *(unsigned*)&Sb[(size_t)n * 128 + d2] = pk;
}

// ---------------- mean pool (batch_ids sorted): wave per 64 nodes ----------------
__global__ void k_pool(const float* __restrict__ h, const int* __restrict__ batch_ids,
                       float* __restrict__ pooled, float* __restrict__ counts, int N) {
  int lane = threadIdx.x & 63;
  int base = blockIdx.x * 64;
  float acc = 0.f;
  int   cnt = 0;
  int  gcur = -1;
  for (int n = 0; n < 64; ++n) {
    int node = base + n;
    if (node >= N) break;
    int g = batch_ids[node];
    if (g != gcur) {
      if (gcur >= 0) {
        atomicAdd(&pooled[gcur * NODE_DIM + lane], acc);
        if (lane == 0) atomicAdd(&counts[gcur], (float)cnt);
      }
      gcur = g; acc = 0.f; cnt = 0;
    }
    acc += h[(size_t)node * NODE_DIM + lane];
    cnt++;
  }
  if (gcur >= 0) {
    atomicAdd(&pooled[gcur * NODE_DIM + lane], acc);
    if (lane == 0) atomicAdd(&counts[gcur], (float)cnt);
  }
}

// final linear: un-permute fc_w (pooled is idx64-permuted)
__global__ void k_final(const float* __restrict__ pooled, const float* __restrict__ counts,
                        const float* __restrict__ fc_w, const float* __restrict__ fc_b,
                        float* __restrict__ out, int G) {
  int g = blockIdx.x * blockDim.x + threadIdx.x;
  if (g < G) {
    float acc = 0.f;
    for (int d = 0; d < NODE_DIM; ++d) {
      int col = (d & 3) * 16 + (d >> 2);      // inverse idx64
      acc += pooled[g * NODE_DIM + d] * fc_w[col];
    }
    float c = counts[g];
    if (c < 1.f) c = 1.f;
    out[g] = acc / c + fc_b[0];
  }
}

extern "C" void kernel_launch(void* const* d_in, const int* in_sizes, int n_in,
                              void* d_out, int out_size, void* d_ws, size_t ws_size,
                              hipStream_t stream) {
  const int*   atoms   = (const int*)  d_in[0];
  const int*   eidx    = (const int*)  d_in[1];
  const float* coords  = (const float*)d_in[2];
  const int*   isr     = (const int*)  d_in[3];
  const int*   batch   = (const int*)  d_in[4];
  const float* embed_w = (const float*)d_in[5];
  const float* sub_w   = (const float*)d_in[6];
  const float* W1      = (const float*)d_in[7];
  const float* b1      = (const float*)d_in[8];
  const float* W2      = (const float*)d_in[9];
  const float* b2      = (const float*)d_in[10];
  const float* fc_w    = (const float*)d_in[11];
  const float* fc_b    = (const float*)d_in[12];
  float* out = (float*)d_out;

  const int N = in_sizes[0];
  const int E = in_sizes[1] / 2;
  const int L = in_sizes[8] / HIDDEN;
  const int G = out_size;

  const int* srcv = eidx;
  const int* dstv = eidx + E;

  size_t off = 0;
  auto carve = [&](size_t bytes) -> char* {
    char* p = (char*)d_ws + off;
    off += (bytes + 255) & ~(size_t)255;
    return p;
  };
  float* hf     = (float*)carve((size_t)N * NODE_DIM * 4);
  short* hb     = (short*)carve((size_t)N * NODE_DIM * 2);
  short* Sb     = (short*)carve((size_t)N * HIDDEN * 2);
  short* pa     = (short*)carve((size_t)N * HIDDEN * 2);
  short* pb     = (short*)carve((size_t)N * HIDDEN * 2);
  int*   ety    = (int*)  carve((size_t)E * 4);
  int*   cnts   = (int*)  carve((size_t)N * 4);
  int*   cursor = (int*)  carve((size_t)N * 4);
  int*   colptr = (int*)  carve(((size_t)N + 2) * 4);
  int*   sd_p   = (int*)  carve((size_t)E * 4);
  int*   part   = (int*)  carve(((size_t)N / 256 + 2) * 4);
  short* W1abp  = (short*)carve((size_t)L * L1ABSZ * 2);
  short* W2p    = (short*)carve((size_t)L * L2SZ * 2);
  short* tbl    = (short*)carve((size_t)L * TBLSZ * 2);
  float* pooled = (float*)carve((size_t)G * NODE_DIM * 4);
  float* cntg   = (float*)carve((size_t)G * 4);

  const int nbN = (N + 255) / 256;

  k_zero_i<<<nbN, 256, 0, stream>>>(cnts, N);
  k_init<<<1024, 256, 0, stream>>>(atoms, embed_w, hf, hb, N * NODE_DIM);
  k_edge_pre<<<1024, 256, 0, stream>>>(srcv, dstv, coords, isr, ety, cnts, E);
  k_zero_f<<<(G * NODE_DIM + G + 255) / 256, 256, 0, stream>>>(pooled, G * NODE_DIM + G);
  k_scan_part<<<nbN, 256, 0, stream>>>(cnts, part, N);
  k_scan_top<<<1, 512, 0, stream>>>(part, nbN);
  k_scan_apply<<<nbN, 256, 0, stream>>>(cnts, part, cursor, colptr, N, E);
  k_build<<<1024, 256, 0, stream>>>(srcv, dstv, ety, cursor, sd_p, E);
  k_pack_w1ab<<<(L * L1ABSZ + 255) / 256, 256, 0, stream>>>(W1, W1abp, L * L1ABSZ);
  k_pack_w2<<<(L * L2SZ + 255) / 256, 256, 0, stream>>>(W2, W2p, L * L2SZ);
  k_tbl<<<(L * 2 * TBL_BINS + 255) / 256, 256, 0, stream>>>(W1, sub_w, tbl, L * 2 * TBL_BINS);

  const int nblk_n = (N + 63) / 64;
  const int nblk_g = (N + 3) / 4;
  for (int l = 0; l < L; ++l) {
    k_node<<<nblk_n, 256, 0, stream>>>(
        hf, hb, Sb, cnts,
        (l > 0) ? W2p + (size_t)(l - 1) * L2SZ : (const short*)nullptr,
        (l > 0) ? b2 + (size_t)(l - 1) * NODE_DIM : (const float*)nullptr,
        W1abp + (size_t)l * L1ABSZ, b1 + (size_t)l * HIDDEN,
        pa, pb, N);
    k_gather<<<nblk_g, 256, 0, stream>>>(pa, pb, tbl + (size_t)l * TBLSZ,
                                         sd_p, colptr, Sb, N);
  }
  k_node<<<nblk_n, 256, 0, stream>>>(
      hf, hb, Sb, cnts,
      W2p + (size_t)(L - 1) * L2SZ, b2 + (size_t)(L - 1) * NODE_DIM,
      (const short*)nullptr, (const float*)nullptr, pa, pb, N);

  k_pool<<<(N + 63) / 64, 64, 0, stream>>>(hf, batch, pooled, cntg, N);
  k_final<<<1, 64, 0, stream>>>(pooled, cntg, fc_w, fc_b, out, G);
}

// Round 16
// 632.485 us; speedup vs baseline: 1.3242x; 1.0937x over previous
//
#include <hip/hip_runtime.h>
#include <hip/hip_bf16.h>
#include <math.h>

#define NODE_DIM  64
#define EDGE_DIM  32
#define NUM_GAUSS 16
#define HIDDEN    128
#define CAT_DIM   160
#define TBL_BINS  2048
#define TBL_SCALE 256.0f                // bins per unit distance (domain [0,8))
#define L1ABSZ    (64 * 256)            // packed W1ab per layer (K=64, N=256)
#define L2SZ      (HIDDEN * NODE_DIM)   // packed W2 per layer   (K=128, N=64)
#define TBLSZ     (2 * TBL_BINS * 128)  // per-layer edge-attr table entries

// Column-permuted storage: idx64(c)=(c&15)*4+(c>>4)  (64-wide: h, hf, hb, ht)
//                          idx128(c)=(c&15)*8+(c>>4) (128-wide: pa, pb, tbl, Sb)
// Weights' K dims are packed with the same permutation, so all GEMMs are invariant.
// Edge record: rec = (src << 12) | ety   (src<2^20, ety<2^12) — single 4 B scatter.

typedef __attribute__((ext_vector_type(8))) short short8;
typedef __attribute__((ext_vector_type(4))) short short4v;
typedef __attribute__((ext_vector_type(4))) float float4v;

static __device__ __forceinline__ short f2bf(float x) {
  __hip_bfloat16 h = __float2bfloat16(x);
  return *reinterpret_cast<short*>(&h);
}
static __device__ __forceinline__ float bflo(unsigned u) { return __uint_as_float(u << 16); }
static __device__ __forceinline__ float bfhi(unsigned u) { return __uint_as_float(u & 0xffff0000u); }

// ---------------- init: h (idx64-permuted) = embed[atoms] ----------------
__global__ void k_init(const int* __restrict__ atoms, const float* __restrict__ embed_w,
                       float* __restrict__ hf, short* __restrict__ hb, int n) {
  int stride = gridDim.x * blockDim.x;
  for (int i = blockIdx.x * blockDim.x + threadIdx.x; i < n; i += stride) {
    int p = i & 63;
    int col = (p & 3) * 16 + (p >> 2);          // inverse idx64
    float f = embed_w[atoms[i >> 6] * NODE_DIM + col];
    hf[i] = f;
    hb[i] = f2bf(f);
  }
}

__global__ void k_zero_f(float* __restrict__ p, int n) {
  int stride = gridDim.x * blockDim.x;
  for (int i = blockIdx.x * blockDim.x + threadIdx.x; i < n; i += stride) p[i] = 0.f;
}
__global__ void k_zero_i(int* __restrict__ p, int n) {
  int i = blockIdx.x * blockDim.x + threadIdx.x;
  if (i < n) p[i] = 0;
}

// ---------------- edge precompute: ety = (kind<<11) | bin(dist); fused dst histogram ----------------
__global__ void k_edge_pre(const int* __restrict__ src, const int* __restrict__ dst,
                           const float* __restrict__ coords, const int* __restrict__ isr,
                           int* __restrict__ ety, int* __restrict__ counts, int E) {
  int stride = gridDim.x * blockDim.x;
  for (int e = blockIdx.x * blockDim.x + threadIdx.x; e < E; e += stride) {
    int s = src[e], d = dst[e];
    float dx = coords[s*3+0] - coords[d*3+0];
    float dy = coords[s*3+1] - coords[d*3+1];
    float dz = coords[s*3+2] - coords[d*3+2];
    float dist = sqrtf(dx*dx + dy*dy + dz*dz);
    int bin = (int)(dist * TBL_SCALE);
    bin = (bin > TBL_BINS - 1) ? TBL_BINS - 1 : bin;
    int kind = (isr[s] != isr[d]) ? 1 : 0;
    ety[e] = (kind << 11) | bin;
    atomicAdd(&counts[d], 1);
  }
}

// ---------------- edge-attr table: thread per OUTPUT ELEMENT (2M threads) ----------------
__global__ void k_tbl(const float* __restrict__ W1, const float* __restrict__ sub_w,
                      short* __restrict__ tbl, int total) {
  int i = blockIdx.x * 256 + threadIdx.x;     // i over [0, L*2*TBL_BINS*128)
  if (i >= total) return;
  int col  = i & 127;
  int idx  = i >> 7;                           // (l, kind, bin)
  int bin  = idx & (TBL_BINS - 1);
  int kind = (idx >> 11) & 1;
  int l    = idx >> 12;
  float dist = ((float)bin + 0.5f) * (1.0f / TBL_SCALE);
  const float* W1c = W1 + (size_t)l * CAT_DIM * HIDDEN + 128 * HIDDEN;
  float acc = 0.f;
  #pragma unroll
  for (int g = 0; g < 16; ++g) {
    float t = dist - (float)g * (1.0f / 3.0f);
    acc += __expf(-4.5f * t * t) * W1c[g * 128 + col];
  }
  #pragma unroll
  for (int g = 0; g < 16; ++g)
    acc += sub_w[kind * 16 + g] * W1c[(16 + g) * 128 + col];
  tbl[(size_t)idx * 128 + (col & 15) * 8 + (col >> 4)] = f2bf(acc);   // idx128
}

// ---------------- CSR build ----------------
__global__ void k_scan_part(const int* __restrict__ counts, int* __restrict__ part, int N) {
  __shared__ int red[256];
  int t = threadIdx.x;
  int i = blockIdx.x * 256 + t;
  red[t] = (i < N) ? counts[i] : 0;
  __syncthreads();
  for (int o = 128; o > 0; o >>= 1) {
    if (t < o) red[t] += red[t + o];
    __syncthreads();
  }
  if (t == 0) part[blockIdx.x] = red[0];
}

__global__ void k_scan_top(int* __restrict__ part, int nb) {
  __shared__ int s[512];
  int t = threadIdx.x;
  int v = (t < nb) ? part[t] : 0;
  s[t] = v;
  __syncthreads();
  for (int o = 1; o < 512; o <<= 1) {
    int u = (t >= o) ? s[t - o] : 0;
    __syncthreads();
    s[t] += u;
    __syncthreads();
  }
  if (t < nb) part[t] = s[t] - v;   // exclusive
}

__global__ void k_scan_apply(const int* __restrict__ counts, const int* __restrict__ part,
                             int* __restrict__ cursor, int* __restrict__ colptr,
                             int N, int E) {
  __shared__ int s[256];
  int t = threadIdx.x;
  int i = blockIdx.x * 256 + t;
  int v = (i < N) ? counts[i] : 0;
  s[t] = v;
  __syncthreads();
  for (int o = 1; o < 256; o <<= 1) {
    int u = (t >= o) ? s[t - o] : 0;
    __syncthreads();
    s[t] += u;
    __syncthreads();
  }
  if (i < N) {
    int ex = part[blockIdx.x] + s[t] - v;   // exclusive prefix
    cursor[i] = ex;
    colptr[i] = ex;
    if (i == N - 1) colptr[N] = E;
  }
}

// scatter packed (src<<12 | ety) records into dst-sorted order (4 B stores)
__global__ void k_build(const int* __restrict__ src, const int* __restrict__ dst,
                        const int* __restrict__ ety, int* __restrict__ cursor,
                        int* __restrict__ sd_p, int E) {
  int stride = gridDim.x * blockDim.x;
  for (int e = blockIdx.x * blockDim.x + threadIdx.x; e < E; e += stride) {
    int d = dst[e];
    int p = atomicAdd(&cursor[d], 1);
    sd_p[p] = (src[e] << 12) | ety[e];
  }
}

// ---------------- weight packing: B-frag order, K permuted to match storage ----------------
__global__ void k_pack_w1ab(const float* __restrict__ W1, short* __restrict__ Wp, int total) {
  int i = blockIdx.x * blockDim.x + threadIdx.x;
  if (i >= total) return;
  int l = i / L1ABSZ, r = i % L1ABSZ;
  int k = r / 256, n = r % 256;                 // k = original h col (0..63)
  int kp = (k & 15) * 4 + (k >> 4);             // idx64
  int kt = kp >> 5, quad = (kp >> 3) & 3, j = kp & 7;
  int srow = (n < 128) ? k : 64 + k;
  int scol = (n < 128) ? n : n - 128;
  Wp[l * L1ABSZ + ((kt*4 + quad) * 256 + n) * 8 + j] =
      f2bf(W1[(size_t)l * CAT_DIM * HIDDEN + srow * HIDDEN + scol]);
}
__global__ void k_pack_w2(const float* __restrict__ W, short* __restrict__ Wp, int total) {
  int i = blockIdx.x * blockDim.x + threadIdx.x;
  if (i >= total) return;
  int l = i / L2SZ, r = i % L2SZ;
  int k = r / NODE_DIM, n = r % NODE_DIM;       // k = original hidden col (0..127)
  int kp = (k & 15) * 8 + (k >> 4);             // idx128
  int kt = kp >> 5, quad = (kp >> 3) & 3, j = kp & 7;
  Wp[l * L2SZ + ((kt*4 + quad) * NODE_DIM + n) * 8 + j] = f2bf(W[i]);
}

// ---------------- node kernel: [agg=Sb@W2+cnt*b2; h=relu(h+agg)] ; [pa|pb = h@W1ab] ----------------
__global__ __launch_bounds__(256, 4) void k_node(
    float* __restrict__ hf, const short* __restrict__ hb,
    const short* __restrict__ Sb, const int* __restrict__ cnts,
    const short* __restrict__ W2p, const float* __restrict__ b2,
    const short* __restrict__ W1abp, const float* __restrict__ b1,
    short* __restrict__ pa, short* __restrict__ pb, int N)
{
  __shared__ short ht[64 * 72];

  const int tid  = threadIdx.x;
  const int lane = tid & 63;
  const int w    = tid >> 6;
  const int quad = lane >> 4;
  const int l16  = lane & 15;
  const int base = blockIdx.x * 64 + w * 16;

  if (W2p) {
    float4v acc[4];
    #pragma unroll
    for (int nt = 0; nt < 4; ++nt) acc[nt] = (float4v)0.f;
    const int arow = base + l16;
    const bool av = arow < N;
    #pragma unroll
    for (int kt = 0; kt < 4; ++kt) {
      short8 a = av ? *(const short8*)&Sb[(size_t)arow * 128 + kt*32 + quad*8]
                    : (short8)0;
      #pragma unroll
      for (int nt = 0; nt < 4; ++nt) {
        short8 b = *(const short8*)&W2p[((kt*4 + quad) * NODE_DIM + nt*16 + l16) * 8];
        acc[nt] = __builtin_amdgcn_mfma_f32_16x16x32_bf16(a, b, acc[nt], 0, 0, 0);
      }
    }
    float bb[4];
    #pragma unroll
    for (int nt = 0; nt < 4; ++nt) bb[nt] = b2[nt*16 + l16];
    #pragma unroll
    for (int r = 0; r < 4; ++r) {
      int row  = base + quad*4 + r;
      int lrow = w*16 + quad*4 + r;
      if (row < N) {
        float cf = (float)cnts[row];
        float4 hv = *(const float4*)&hf[(size_t)row * 64 + l16*4];   // permuted pos l16*4+nt
        float v0 = fmaxf(hv.x + acc[0][r] + cf * bb[0], 0.f);
        float v1 = fmaxf(hv.y + acc[1][r] + cf * bb[1], 0.f);
        float v2 = fmaxf(hv.z + acc[2][r] + cf * bb[2], 0.f);
        float v3 = fmaxf(hv.w + acc[3][r] + cf * bb[3], 0.f);
        *(float4*)&hf[(size_t)row * 64 + l16*4] = make_float4(v0, v1, v2, v3);
        short4v hs = {f2bf(v0), f2bf(v1), f2bf(v2), f2bf(v3)};
        *(short4v*)&ht[lrow * 72 + l16*4] = hs;
      } else {
        *(short4v*)&ht[lrow * 72 + l16*4] = (short4v)0;
      }
    }
  } else {
    int row = base + l16;
    #pragma unroll
    for (int c = 0; c < 2; ++c) {
      int colc = quad*16 + c*8;
      short8 v = (row < N) ? *(const short8*)&hb[(size_t)row * 64 + colc] : (short8)0;
      *(short8*)&ht[(w*16 + l16) * 72 + colc] = v;
    }
  }

  if (W1abp) {
    float4v acc[16];
    #pragma unroll
    for (int nt = 0; nt < 16; ++nt) acc[nt] = (float4v)0.f;
    #pragma unroll
    for (int kt = 0; kt < 2; ++kt) {
      short8 a = *(const short8*)&ht[(w*16 + l16) * 72 + kt*32 + quad*8];
      #pragma unroll
      for (int nt = 0; nt < 16; ++nt) {
        short8 b = *(const short8*)&W1abp[((kt*4 + quad) * 256 + nt*16 + l16) * 8];
        acc[nt] = __builtin_amdgcn_mfma_f32_16x16x32_bf16(a, b, acc[nt], 0, 0, 0);
      }
    }
    float b1a[8];
    #pragma unroll
    for (int nt = 0; nt < 8; ++nt) b1a[nt] = b1[nt*16 + l16];
    #pragma unroll
    for (int r = 0; r < 4; ++r) {
      int row = base + quad*4 + r;
      if (row < N) {
        short8 va, vb;
        #pragma unroll
        for (int nt = 0; nt < 8; ++nt) va[nt] = f2bf(acc[nt][r] + b1a[nt]);
        #pragma unroll
        for (int nt = 0; nt < 8; ++nt) vb[nt] = f2bf(acc[nt + 8][r]);
        *(short8*)&pa[(size_t)row * 128 + l16*8] = va;   // permuted pos l16*8+nt
        *(short8*)&pb[(size_t)row * 128 + l16*8] = vb;
      }
    }
  }
}

// ---------------- gather kernel: wave per node, 4-deep double-buffered CSR gather ----------------
__global__ __launch_bounds__(256, 8) void k_gather(
    const short* __restrict__ pa, const short* __restrict__ pb,
    const short* __restrict__ tblL,
    const int* __restrict__ sd_p, const int* __restrict__ colptr,
    short* __restrict__ Sb, int N)
{
  int n = blockIdx.x * 4 + (threadIdx.x >> 6);
  if (n >= N) return;
  const int lane = threadIdx.x & 63;
  const int d2 = lane * 2;

  const int s = colptr[n];
  const int e = colptr[n + 1];

  unsigned up = *(const unsigned*)&pa[(size_t)n * 128 + d2];
  const float p0 = bflo(up), p1 = bfhi(up);
  float s0 = 0.f, s1 = 0.f;

  const char* pbB = (const char*)pb + d2 * 2;
  const char* tbB = (const char*)tblL + d2 * 2;

  if (e > s) {
    unsigned ub0[4], ue0[4], ub1[4], ue1[4];

    auto load4 = [&](unsigned (&ub)[4], unsigned (&ue)[4], int j) {
      #pragma unroll
      for (int t = 0; t < 4; ++t) {
        int jj = (j + t < e) ? j + t : s;       // clamp: always a valid record
        int rc = __builtin_amdgcn_readfirstlane(sd_p[jj]);  // wave-uniform scalar
        int so = (rc >> 12) << 8;               // src byte offset (256 B rows)
        int to = (rc & 0xfff) << 8;             // ety byte offset
        ub[t] = *(const unsigned*)(pbB + so);
        ue[t] = *(const unsigned*)(tbB + to);
      }
    };
    auto consume4 = [&](unsigned (&ub)[4], unsigned (&ue)[4], int j) {
      #pragma unroll
      for (int t = 0; t < 4; ++t) {
        if (j + t < e) {
          float x0 = p0 + bflo(ub[t]) + bflo(ue[t]);
          float x1 = p1 + bfhi(ub[t]) + bfhi(ue[t]);
          s0 += x0 * __builtin_amdgcn_rcpf(1.f + __expf(-x0));
          s1 += x1 * __builtin_amdgcn_rcpf(1.f + __expf(-x1));
        }
      }
    };

    load4(ub0, ue0, s);
    int j = s;
    for (; j + 4 < e; j += 8) {
      load4(ub1, ue1, j + 4);
      consume4(ub0, ue0, j);
      if (j + 8 < e) load4(ub0, ue0, j + 8);
      consume4(ub1, ue1, j + 4);
    }
    if (j < e) consume4(ub0, ue0, j);
  }

  unsigned pk = ((unsigned)(unsigned short)f2bf(s1) << 16) | (unsigned short)f2bf(s0);
  *(unsigned*)&Sb[(size_t)n * 128 + d2] = pk;
}

// ---------------- mean pool (batch_ids sorted): wave per 64 nodes ----------------
__global__ void k_pool(const float* __restrict__ h, const int* __restrict__ batch_ids,
                       float* __restrict__ pooled, float* __restrict__ counts, int N) {
  int lane = threadIdx.x & 63;
  int base = blockIdx.x * 64;
  float acc = 0.f;
  int   cnt = 0;
  int  gcur = -1;
  for (int n = 0; n < 64; ++n) {
    int node = base + n;
    if (node >= N) break;
    int g = batch_ids[node];
    if (g != gcur) {
      if (gcur >= 0) {
        atomicAdd(&pooled[gcur * NODE_DIM + lane], acc);
        if (lane == 0) atomicAdd(&counts[gcur], (float)cnt);
      }
      gcur = g; acc = 0.f; cnt = 0;
    }
    acc += h[(size_t)node * NODE_DIM + lane];
    cnt++;
  }
  if (gcur >= 0) {
    atomicAdd(&pooled[gcur * NODE_DIM + lane], acc);
    if (lane == 0) atomicAdd(&counts[gcur], (float)cnt);
  }
}

// final linear: un-permute fc_w (pooled is idx64-permuted)
__global__ void k_final(const float* __restrict__ pooled, const float* __restrict__ counts,
                        const float* __restrict__ fc_w, const float* __restrict__ fc_b,
                        float* __restrict__ out, int G) {
  int g = blockIdx.x * blockDim.x + threadIdx.x;
  if (g < G) {
    float acc = 0.f;
    for (int d = 0; d < NODE_DIM; ++d) {
      int col = (d & 3) * 16 + (d >> 2);      // inverse idx64
      acc += pooled[g * NODE_DIM + d] * fc_w[col];
    }
    float c = counts[g];
    if (c < 1.f) c = 1.f;
    out[g] = acc / c + fc_b[0];
  }
}

extern "C" void kernel_launch(void* const* d_in, const int* in_sizes, int n_in,
                              void* d_out, int out_size, void* d_ws, size_t ws_size,
                              hipStream_t stream) {
  const int*   atoms   = (const int*)  d_in[0];
  const int*   eidx    = (const int*)  d_in[1];
  const float* coords  = (const float*)d_in[2];
  const int*   isr     = (const int*)  d_in[3];
  const int*   batch   = (const int*)  d_in[4];
  const float* embed_w = (const float*)d_in[5];
  const float* sub_w   = (const float*)d_in[6];
  const float* W1      = (const float*)d_in[7];
  const float* b1      = (const float*)d_in[8];
  const float* W2      = (const float*)d_in[9];
  const float* b2      = (const float*)d_in[10];
  const float* fc_w    = (const float*)d_in[11];
  const float* fc_b    = (const float*)d_in[12];
  float* out = (float*)d_out;

  const int N = in_sizes[0];
  const int E = in_sizes[1] / 2;
  const int L = in_sizes[8] / HIDDEN;
  const int G = out_size;

  const int* srcv = eidx;
  const int* dstv = eidx + E;

  size_t off = 0;
  auto carve = [&](size_t bytes) -> char* {
    char* p = (char*)d_ws + off;
    off += (bytes + 255) & ~(size_t)255;
    return p;
  };
  float* hf     = (float*)carve((size_t)N * NODE_DIM * 4);
  short* hb     = (short*)carve((size_t)N * NODE_DIM * 2);
  short* Sb     = (short*)carve((size_t)N * HIDDEN * 2);
  short* pa     = (short*)carve((size_t)N * HIDDEN * 2);
  short* pb     = (short*)carve((size_t)N * HIDDEN * 2);
  int*   ety    = (int*)  carve((size_t)E * 4);
  int*   cnts   = (int*)  carve((size_t)N * 4);
  int*   cursor = (int*)  carve((size_t)N * 4);
  int*   colptr = (int*)  carve(((size_t)N + 2) * 4);
  int*   sd_p   = (int*)  carve((size_t)E * 4);
  int*   part   = (int*)  carve(((size_t)N / 256 + 2) * 4);
  short* W1abp  = (short*)carve((size_t)L * L1ABSZ * 2);
  short* W2p    = (short*)carve((size_t)L * L2SZ * 2);
  short* tbl    = (short*)carve((size_t)L * TBLSZ * 2);
  float* pooled = (float*)carve((size_t)G * NODE_DIM * 4);
  float* cntg   = (float*)carve((size_t)G * 4);

  const int nbN = (N + 255) / 256;

  k_zero_i<<<nbN, 256, 0, stream>>>(cnts, N);
  k_init<<<1024, 256, 0, stream>>>(atoms, embed_w, hf, hb, N * NODE_DIM);
  k_edge_pre<<<4096, 256, 0, stream>>>(srcv, dstv, coords, isr, ety, cnts, E);
  k_zero_f<<<(G * NODE_DIM + G + 255) / 256, 256, 0, stream>>>(pooled, G * NODE_DIM + G);
  k_scan_part<<<nbN, 256, 0, stream>>>(cnts, part, N);
  k_scan_top<<<1, 512, 0, stream>>>(part, nbN);
  k_scan_apply<<<nbN, 256, 0, stream>>>(cnts, part, cursor, colptr, N, E);
  k_build<<<4096, 256, 0, stream>>>(srcv, dstv, ety, cursor, sd_p, E);
  k_pack_w1ab<<<(L * L1ABSZ + 255) / 256, 256, 0, stream>>>(W1, W1abp, L * L1ABSZ);
  k_pack_w2<<<(L * L2SZ + 255) / 256, 256, 0, stream>>>(W2, W2p, L * L2SZ);
  k_tbl<<<(L * 2 * TBL_BINS * 128 + 255) / 256, 256, 0, stream>>>(W1, sub_w, tbl,
                                                                  L * 2 * TBL_BINS * 128);

  const int nblk_n = (N + 63) / 64;
  const int nblk_g = (N + 3) / 4;
  for (int l = 0; l < L; ++l) {
    k_node<<<nblk_n, 256, 0, stream>>>(
        hf, hb, Sb, cnts,
        (l > 0) ? W2p + (size_t)(l - 1) * L2SZ : (const short*)nullptr,
        (l > 0) ? b2 + (size_t)(l - 1) * NODE_DIM : (const float*)nullptr,
        W1abp + (size_t)l * L1ABSZ, b1 + (size_t)l * HIDDEN,
        pa, pb, N);
    k_gather<<<nblk_g, 256, 0, stream>>>(pa, pb, tbl + (size_t)l * TBLSZ,
                                         sd_p, colptr, Sb, N);
  }
  k_node<<<nblk_n, 256, 0, stream>>>(
      hf, hb, Sb, cnts,
      W2p + (size_t)(L - 1) * L2SZ, b2 + (size_t)(L - 1) * NODE_DIM,
      (const short*)nullptr, (const float*)nullptr, pa, pb, N);

  k_pool<<<(N + 63) / 64, 64, 0, stream>>>(hf, batch, pooled, cntg, N);
  k_final<<<1, 64, 0, stream>>>(pooled, cntg, fc_w, fc_b, out, G);
}

// Round 17
// 631.231 us; speedup vs baseline: 1.3269x; 1.0020x over previous
//
#include <hip/hip_runtime.h>
#include <hip/hip_bf16.h>
#include <math.h>

#define NODE_DIM  64
#define EDGE_DIM  32
#define NUM_GAUSS 16
#define HIDDEN    128
#define CAT_DIM   160
#define TBL_BINS  2048
#define TBL_SCALE 256.0f                // bins per unit distance (domain [0,8))
#define L1ABSZ    (64 * 256)            // packed W1ab per layer (K=64, N=256)
#define L2SZ      (HIDDEN * NODE_DIM)   // packed W2 per layer   (K=128, N=64)
#define TBLSZ     (2 * TBL_BINS * 128)  // per-layer edge-attr table entries

// Column-permuted storage: idx64(c)=(c&15)*4+(c>>4)  (64-wide: hb, ht)
//                          idx128(c)=(c&15)*8+(c>>4) (128-wide: pa, pb, tbl, Sb)
// Weights' K dims are packed with the same permutation, so all GEMMs are invariant.
// Edge record: rec = (src << 12) | ety   (src<2^20, ety<2^12) — single 4 B scatter.
// h is carried in bf16 only (hb); fp32 carry dropped (tolerance 0.3075 >> bf16 drift).

typedef __attribute__((ext_vector_type(8))) short short8;
typedef __attribute__((ext_vector_type(4))) short short4v;
typedef __attribute__((ext_vector_type(4))) float float4v;

static __device__ __forceinline__ short f2bf(float x) {
  __hip_bfloat16 h = __float2bfloat16(x);
  return *reinterpret_cast<short*>(&h);
}
static __device__ __forceinline__ float bf2f(short s) {
  return __uint_as_float(((unsigned)(unsigned short)s) << 16);
}
static __device__ __forceinline__ float bflo(unsigned u) { return __uint_as_float(u << 16); }
static __device__ __forceinline__ float bfhi(unsigned u) { return __uint_as_float(u & 0xffff0000u); }

// ---------------- init: hb (idx64-permuted) = embed[atoms] ----------------
__global__ void k_init(const int* __restrict__ atoms, const float* __restrict__ embed_w,
                       short* __restrict__ hb, int n) {
  int stride = gridDim.x * blockDim.x;
  for (int i = blockIdx.x * blockDim.x + threadIdx.x; i < n; i += stride) {
    int p = i & 63;
    int col = (p & 3) * 16 + (p >> 2);          // inverse idx64
    hb[i] = f2bf(embed_w[atoms[i >> 6] * NODE_DIM + col]);
  }
}

__global__ void k_zero_f(float* __restrict__ p, int n) {
  int stride = gridDim.x * blockDim.x;
  for (int i = blockIdx.x * blockDim.x + threadIdx.x; i < n; i += stride) p[i] = 0.f;
}
__global__ void k_zero_i(int* __restrict__ p, int n) {
  int i = blockIdx.x * blockDim.x + threadIdx.x;
  if (i < n) p[i] = 0;
}

// ---------------- edge precompute: ety = (kind<<11) | bin(dist); fused dst histogram ----------------
__global__ void k_edge_pre(const int* __restrict__ src, const int* __restrict__ dst,
                           const float* __restrict__ coords, const int* __restrict__ isr,
                           int* __restrict__ ety, int* __restrict__ counts, int E) {
  int stride = gridDim.x * blockDim.x;
  for (int e = blockIdx.x * blockDim.x + threadIdx.x; e < E; e += stride) {
    int s = src[e], d = dst[e];
    float dx = coords[s*3+0] - coords[d*3+0];
    float dy = coords[s*3+1] - coords[d*3+1];
    float dz = coords[s*3+2] - coords[d*3+2];
    float dist = sqrtf(dx*dx + dy*dy + dz*dz);
    int bin = (int)(dist * TBL_SCALE);
    bin = (bin > TBL_BINS - 1) ? TBL_BINS - 1 : bin;
    int kind = (isr[s] != isr[d]) ? 1 : 0;
    ety[e] = (kind << 11) | bin;
    atomicAdd(&counts[d], 1);
  }
}

// ---------------- edge-attr table: thread per OUTPUT ELEMENT (2M threads) ----------------
__global__ void k_tbl(const float* __restrict__ W1, const float* __restrict__ sub_w,
                      short* __restrict__ tbl, int total) {
  int i = blockIdx.x * 256 + threadIdx.x;     // i over [0, L*2*TBL_BINS*128)
  if (i >= total) return;
  int col  = i & 127;
  int idx  = i >> 7;                           // (l, kind, bin)
  int bin  = idx & (TBL_BINS - 1);
  int kind = (idx >> 11) & 1;
  int l    = idx >> 12;
  float dist = ((float)bin + 0.5f) * (1.0f / TBL_SCALE);
  const float* W1c = W1 + (size_t)l * CAT_DIM * HIDDEN + 128 * HIDDEN;
  float acc = 0.f;
  #pragma unroll
  for (int g = 0; g < 16; ++g) {
    float t = dist - (float)g * (1.0f / 3.0f);
    acc += __expf(-4.5f * t * t) * W1c[g * 128 + col];
  }
  #pragma unroll
  for (int g = 0; g < 16; ++g)
    acc += sub_w[kind * 16 + g] * W1c[(16 + g) * 128 + col];
  tbl[(size_t)idx * 128 + (col & 15) * 8 + (col >> 4)] = f2bf(acc);   // idx128
}

// ---------------- CSR build ----------------
__global__ void k_scan_part(const int* __restrict__ counts, int* __restrict__ part, int N) {
  __shared__ int red[256];
  int t = threadIdx.x;
  int i = blockIdx.x * 256 + t;
  red[t] = (i < N) ? counts[i] : 0;
  __syncthreads();
  for (int o = 128; o > 0; o >>= 1) {
    if (t < o) red[t] += red[t + o];
    __syncthreads();
  }
  if (t == 0) part[blockIdx.x] = red[0];
}

__global__ void k_scan_top(int* __restrict__ part, int nb) {
  __shared__ int s[512];
  int t = threadIdx.x;
  int v = (t < nb) ? part[t] : 0;
  s[t] = v;
  __syncthreads();
  for (int o = 1; o < 512; o <<= 1) {
    int u = (t >= o) ? s[t - o] : 0;
    __syncthreads();
    s[t] += u;
    __syncthreads();
  }
  if (t < nb) part[t] = s[t] - v;   // exclusive
}

__global__ void k_scan_apply(const int* __restrict__ counts, const int* __restrict__ part,
                             int* __restrict__ cursor, int* __restrict__ colptr,
                             int N, int E) {
  __shared__ int s[256];
  int t = threadIdx.x;
  int i = blockIdx.x * 256 + t;
  int v = (i < N) ? counts[i] : 0;
  s[t] = v;
  __syncthreads();
  for (int o = 1; o < 256; o <<= 1) {
    int u = (t >= o) ? s[t - o] : 0;
    __syncthreads();
    s[t] += u;
    __syncthreads();
  }
  if (i < N) {
    int ex = part[blockIdx.x] + s[t] - v;   // exclusive prefix
    cursor[i] = ex;
    colptr[i] = ex;
    if (i == N - 1) colptr[N] = E;
  }
}

// scatter packed (src<<12 | ety) records into dst-sorted order (nt 4 B stores)
__global__ void k_build(const int* __restrict__ src, const int* __restrict__ dst,
                        const int* __restrict__ ety, int* __restrict__ cursor,
                        int* __restrict__ sd_p, int E) {
  int stride = gridDim.x * blockDim.x;
  for (int e = blockIdx.x * blockDim.x + threadIdx.x; e < E; e += stride) {
    int d = dst[e];
    int p = atomicAdd(&cursor[d], 1);
    __builtin_nontemporal_store((src[e] << 12) | ety[e], &sd_p[p]);
  }
}

// ---------------- weight packing: B-frag order, K permuted to match storage ----------------
__global__ void k_pack_w1ab(const float* __restrict__ W1, short* __restrict__ Wp, int total) {
  int i = blockIdx.x * blockDim.x + threadIdx.x;
  if (i >= total) return;
  int l = i / L1ABSZ, r = i % L1ABSZ;
  int k = r / 256, n = r % 256;                 // k = original h col (0..63)
  int kp = (k & 15) * 4 + (k >> 4);             // idx64
  int kt = kp >> 5, quad = (kp >> 3) & 3, j = kp & 7;
  int srow = (n < 128) ? k : 64 + k;
  int scol = (n < 128) ? n : n - 128;
  Wp[l * L1ABSZ + ((kt*4 + quad) * 256 + n) * 8 + j] =
      f2bf(W1[(size_t)l * CAT_DIM * HIDDEN + srow * HIDDEN + scol]);
}
__global__ void k_pack_w2(const float* __restrict__ W, short* __restrict__ Wp, int total) {
  int i = blockIdx.x * blockDim.x + threadIdx.x;
  if (i >= total) return;
  int l = i / L2SZ, r = i % L2SZ;
  int k = r / NODE_DIM, n = r % NODE_DIM;       // k = original hidden col (0..127)
  int kp = (k & 15) * 8 + (k >> 4);             // idx128
  int kt = kp >> 5, quad = (kp >> 3) & 3, j = kp & 7;
  Wp[l * L2SZ + ((kt*4 + quad) * NODE_DIM + n) * 8 + j] = f2bf(W[i]);
}

// ---------------- node kernel: [agg=Sb@W2+cnt*b2; h=relu(h+agg)] ; [pa|pb = h@W1ab] ----------------
__global__ __launch_bounds__(256, 4) void k_node(
    short* __restrict__ hb,
    const short* __restrict__ Sb, const int* __restrict__ cnts,
    const short* __restrict__ W2p, const float* __restrict__ b2,
    const short* __restrict__ W1abp, const float* __restrict__ b1,
    short* __restrict__ pa, short* __restrict__ pb, int N)
{
  __shared__ short ht[64 * 72];

  const int tid  = threadIdx.x;
  const int lane = tid & 63;
  const int w    = tid >> 6;
  const int quad = lane >> 4;
  const int l16  = lane & 15;
  const int base = blockIdx.x * 64 + w * 16;

  if (W2p) {
    float4v acc[4];
    #pragma unroll
    for (int nt = 0; nt < 4; ++nt) acc[nt] = (float4v)0.f;
    const int arow = base + l16;
    const bool av = arow < N;
    #pragma unroll
    for (int kt = 0; kt < 4; ++kt) {
      short8 a = av ? *(const short8*)&Sb[(size_t)arow * 128 + kt*32 + quad*8]
                    : (short8)0;
      #pragma unroll
      for (int nt = 0; nt < 4; ++nt) {
        short8 b = *(const short8*)&W2p[((kt*4 + quad) * NODE_DIM + nt*16 + l16) * 8];
        acc[nt] = __builtin_amdgcn_mfma_f32_16x16x32_bf16(a, b, acc[nt], 0, 0, 0);
      }
    }
    float bb[4];
    #pragma unroll
    for (int nt = 0; nt < 4; ++nt) bb[nt] = b2[nt*16 + l16];
    #pragma unroll
    for (int r = 0; r < 4; ++r) {
      int row  = base + quad*4 + r;
      int lrow = w*16 + quad*4 + r;
      if (row < N) {
        float cf = (float)cnts[row];
        short4v hv = *(const short4v*)&hb[(size_t)row * 64 + l16*4];  // permuted pos l16*4+nt
        float v0 = fmaxf(bf2f(hv[0]) + acc[0][r] + cf * bb[0], 0.f);
        float v1 = fmaxf(bf2f(hv[1]) + acc[1][r] + cf * bb[1], 0.f);
        float v2 = fmaxf(bf2f(hv[2]) + acc[2][r] + cf * bb[2], 0.f);
        float v3 = fmaxf(bf2f(hv[3]) + acc[3][r] + cf * bb[3], 0.f);
        short4v hs = {f2bf(v0), f2bf(v1), f2bf(v2), f2bf(v3)};
        *(short4v*)&hb[(size_t)row * 64 + l16*4] = hs;
        *(short4v*)&ht[lrow * 72 + l16*4] = hs;
      } else {
        *(short4v*)&ht[lrow * 72 + l16*4] = (short4v)0;
      }
    }
  } else {
    int row = base + l16;
    #pragma unroll
    for (int c = 0; c < 2; ++c) {
      int colc = quad*16 + c*8;
      short8 v = (row < N) ? *(const short8*)&hb[(size_t)row * 64 + colc] : (short8)0;
      *(short8*)&ht[(w*16 + l16) * 72 + colc] = v;
    }
  }

  if (W1abp) {
    float4v acc[16];
    #pragma unroll
    for (int nt = 0; nt < 16; ++nt) acc[nt] = (float4v)0.f;
    #pragma unroll
    for (int kt = 0; kt < 2; ++kt) {
      short8 a = *(const short8*)&ht[(w*16 + l16) * 72 + kt*32 + quad*8];
      #pragma unroll
      for (int nt = 0; nt < 16; ++nt) {
        short8 b = *(const short8*)&W1abp[((kt*4 + quad) * 256 + nt*16 + l16) * 8];
        acc[nt] = __builtin_amdgcn_mfma_f32_16x16x32_bf16(a, b, acc[nt], 0, 0, 0);
      }
    }
    float b1a[8];
    #pragma unroll
    for (int nt = 0; nt < 8; ++nt) b1a[nt] = b1[nt*16 + l16];
    #pragma unroll
    for (int r = 0; r < 4; ++r) {
      int row = base + quad*4 + r;
      if (row < N) {
        short8 va, vb;
        #pragma unroll
        for (int nt = 0; nt < 8; ++nt) va[nt] = f2bf(acc[nt][r] + b1a[nt]);
        #pragma unroll
        for (int nt = 0; nt < 8; ++nt) vb[nt] = f2bf(acc[nt + 8][r]);
        *(short8*)&pa[(size_t)row * 128 + l16*8] = va;   // permuted pos l16*8+nt
        *(short8*)&pb[(size_t)row * 128 + l16*8] = vb;
      }
    }
  }
}

// ---------------- gather kernel: wave per node, 4-deep double-buffered CSR gather ----------------
__global__ __launch_bounds__(256, 8) void k_gather(
    const short* __restrict__ pa, const short* __restrict__ pb,
    const short* __restrict__ tblL,
    const int* __restrict__ sd_p, const int* __restrict__ colptr,
    short* __restrict__ Sb, int N)
{
  int n = blockIdx.x * 4 + (threadIdx.x >> 6);
  if (n >= N) return;
  const int lane = threadIdx.x & 63;
  const int d2 = lane * 2;

  const int s = colptr[n];
  const int e = colptr[n + 1];

  unsigned up = *(const unsigned*)&pa[(size_t)n * 128 + d2];
  const float p0 = bflo(up), p1 = bfhi(up);
  float s0 = 0.f, s1 = 0.f;

  const char* pbB = (const char*)pb + d2 * 2;
  const char* tbB = (const char*)tblL + d2 * 2;

  if (e > s) {
    unsigned ub0[4], ue0[4], ub1[4], ue1[4];

    auto load4 = [&](unsigned (&ub)[4], unsigned (&ue)[4], int j) {
      #pragma unroll
      for (int t = 0; t < 4; ++t) {
        int jj = (j + t < e) ? j + t : s;       // clamp: always a valid record
        int rc = __builtin_amdgcn_readfirstlane(sd_p[jj]);  // wave-uniform scalar
        int so = (rc >> 12) << 8;               // src byte offset (256 B rows)
        int to = (rc & 0xfff) << 8;             // ety byte offset
        ub[t] = *(const unsigned*)(pbB + so);
        ue[t] = *(const unsigned*)(tbB + to);
      }
    };
    auto consume4 = [&](unsigned (&ub)[4], unsigned (&ue)[4], int j) {
      #pragma unroll
      for (int t = 0; t < 4; ++t) {
        if (j + t < e) {
          float x0 = p0 + bflo(ub[t]) + bflo(ue[t]);
          float x1 = p1 + bfhi(ub[t]) + bfhi(ue[t]);
          s0 += x0 * __builtin_amdgcn_rcpf(1.f + __expf(-x0));
          s1 += x1 * __builtin_amdgcn_rcpf(1.f + __expf(-x1));
        }
      }
    };

    load4(ub0, ue0, s);
    int j = s;
    for (; j + 4 < e; j += 8) {
      load4(ub1, ue1, j + 4);
      consume4(ub0, ue0, j);
      if (j + 8 < e) load4(ub0, ue0, j + 8);
      consume4(ub1, ue1, j + 4);
    }
    if (j < e) consume4(ub0, ue0, j);
  }

  unsigned pk = ((unsigned)(unsigned short)f2bf(s1) << 16) | (unsigned short)f2bf(s0);
  *(unsigned*)&Sb[(size_t)n * 128 + d2] = pk;
}

// ---------------- mean pool (batch_ids sorted): wave per 64 nodes, bf16 h ----------------
__global__ void k_pool(const short* __restrict__ hb, const int* __restrict__ batch_ids,
                       float* __restrict__ pooled, float* __restrict__ counts, int N) {
  int lane = threadIdx.x & 63;
  int base = blockIdx.x * 64;
  float acc = 0.f;
  int   cnt = 0;
  int  gcur = -1;
  for (int n = 0; n < 64; ++n) {
    int node = base + n;
    if (node >= N) break;
    int g = batch_ids[node];
    if (g != gcur) {
      if (gcur >= 0) {
        atomicAdd(&pooled[gcur * NODE_DIM + lane], acc);
        if (lane == 0) atomicAdd(&counts[gcur], (float)cnt);
      }
      gcur = g; acc = 0.f; cnt = 0;
    }
    acc += bf2f(hb[(size_t)node * NODE_DIM + lane]);
    cnt++;
  }
  if (gcur >= 0) {
    atomicAdd(&pooled[gcur * NODE_DIM + lane], acc);
    if (lane == 0) atomicAdd(&counts[gcur], (float)cnt);
  }
}

// final linear: un-permute fc_w (pooled is idx64-permuted)
__global__ void k_final(const float* __restrict__ pooled, const float* __restrict__ counts,
                        const float* __restrict__ fc_w, const float* __restrict__ fc_b,
                        float* __restrict__ out, int G) {
  int g = blockIdx.x * blockDim.x + threadIdx.x;
  if (g < G) {
    float acc = 0.f;
    for (int d = 0; d < NODE_DIM; ++d) {
      int col = (d & 3) * 16 + (d >> 2);      // inverse idx64
      acc += pooled[g * NODE_DIM + d] * fc_w[col];
    }
    float c = counts[g];
    if (c < 1.f) c = 1.f;
    out[g] = acc / c + fc_b[0];
  }
}

extern "C" void kernel_launch(void* const* d_in, const int* in_sizes, int n_in,
                              void* d_out, int out_size, void* d_ws, size_t ws_size,
                              hipStream_t stream) {
  const int*   atoms   = (const int*)  d_in[0];
  const int*   eidx    = (const int*)  d_in[1];
  const float* coords  = (const float*)d_in[2];
  const int*   isr     = (const int*)  d_in[3];
  const int*   batch   = (const int*)  d_in[4];
  const float* embed_w = (const float*)d_in[5];
  const float* sub_w   = (const float*)d_in[6];
  const float* W1      = (const float*)d_in[7];
  const float* b1      = (const float*)d_in[8];
  const float* W2      = (const float*)d_in[9];
  const float* b2      = (const float*)d_in[10];
  const float* fc_w    = (const float*)d_in[11];
  const float* fc_b    = (const float*)d_in[12];
  float* out = (float*)d_out;

  const int N = in_sizes[0];
  const int E = in_sizes[1] / 2;
  const int L = in_sizes[8] / HIDDEN;
  const int G = out_size;

  const int* srcv = eidx;
  const int* dstv = eidx + E;

  size_t off = 0;
  auto carve = [&](size_t bytes) -> char* {
    char* p = (char*)d_ws + off;
    off += (bytes + 255) & ~(size_t)255;
    return p;
  };
  short* hb     = (short*)carve((size_t)N * NODE_DIM * 2);
  short* Sb     = (short*)carve((size_t)N * HIDDEN * 2);
  short* pa     = (short*)carve((size_t)N * HIDDEN * 2);
  short* pb     = (short*)carve((size_t)N * HIDDEN * 2);
  int*   ety    = (int*)  carve((size_t)E * 4);
  int*   cnts   = (int*)  carve((size_t)N * 4);
  int*   cursor = (int*)  carve((size_t)N * 4);
  int*   colptr = (int*)  carve(((size_t)N + 2) * 4);
  int*   sd_p   = (int*)  carve((size_t)E * 4);
  int*   part   = (int*)  carve(((size_t)N / 256 + 2) * 4);
  short* W1abp  = (short*)carve((size_t)L * L1ABSZ * 2);
  short* W2p    = (short*)carve((size_t)L * L2SZ * 2);
  short* tbl    = (short*)carve((size_t)L * TBLSZ * 2);
  float* pooled = (float*)carve((size_t)G * NODE_DIM * 4);
  float* cntg   = (float*)carve((size_t)G * 4);

  const int nbN = (N + 255) / 256;

  k_zero_i<<<nbN, 256, 0, stream>>>(cnts, N);
  k_init<<<1024, 256, 0, stream>>>(atoms, embed_w, hb, N * NODE_DIM);
  k_edge_pre<<<4096, 256, 0, stream>>>(srcv, dstv, coords, isr, ety, cnts, E);
  k_zero_f<<<(G * NODE_DIM + G + 255) / 256, 256, 0, stream>>>(pooled, G * NODE_DIM + G);
  k_scan_part<<<nbN, 256, 0, stream>>>(cnts, part, N);
  k_scan_top<<<1, 512, 0, stream>>>(part, nbN);
  k_scan_apply<<<nbN, 256, 0, stream>>>(cnts, part, cursor, colptr, N, E);
  k_build<<<4096, 256, 0, stream>>>(srcv, dstv, ety, cursor, sd_p, E);
  k_pack_w1ab<<<(L * L1ABSZ + 255) / 256, 256, 0, stream>>>(W1, W1abp, L * L1ABSZ);
  k_pack_w2<<<(L * L2SZ + 255) / 256, 256, 0, stream>>>(W2, W2p, L * L2SZ);
  k_tbl<<<(L * 2 * TBL_BINS * 128 + 255) / 256, 256, 0, stream>>>(W1, sub_w, tbl,
                                                                  L * 2 * TBL_BINS * 128);

  const int nblk_n = (N + 63) / 64;
  const int nblk_g = (N + 3) / 4;
  for (int l = 0; l < L; ++l) {
    k_node<<<nblk_n, 256, 0, stream>>>(
        hb, Sb, cnts,
        (l > 0) ? W2p + (size_t)(l - 1) * L2SZ : (const short*)nullptr,
        (l > 0) ? b2 + (size_t)(l - 1) * NODE_DIM : (const float*)nullptr,
        W1abp + (size_t)l * L1ABSZ, b1 + (size_t)l * HIDDEN,
        pa, pb, N);
    k_gather<<<nblk_g, 256, 0, stream>>>(pa, pb, tbl + (size_t)l * TBLSZ,
                                         sd_p, colptr, Sb, N);
  }
  k_node<<<nblk_n, 256, 0, stream>>>(
      hb, Sb, cnts,
      W2p + (size_t)(L - 1) * L2SZ, b2 + (size_t)(L - 1) * NODE_DIM,
      (const short*)nullptr, (const float*)nullptr, pa, pb, N);

  k_pool<<<(N + 63) / 64, 64, 0, stream>>>(hb, batch, pooled, cntg, N);
  k_final<<<1, 64, 0, stream>>>(pooled, cntg, fc_w, fc_b, out, G);
}

// Round 18
// 623.568 us; speedup vs baseline: 1.3432x; 1.0123x over previous
//
#include <hip/hip_runtime.h>
#include <hip/hip_bf16.h>
#include <math.h>

#define NODE_DIM  64
#define EDGE_DIM  32
#define NUM_GAUSS 16
#define HIDDEN    128
#define CAT_DIM   160
#define TBL_BINS  2048
#define TBL_SCALE 256.0f                // bins per unit distance (domain [0,8))
#define L1ABSZ    (64 * 256)            // packed W1ab per layer (K=64, N=256)
#define L2SZ      (HIDDEN * NODE_DIM)   // packed W2 per layer   (K=128, N=64)
#define TBLSZ     (2 * TBL_BINS * 128)  // per-layer edge-attr table entries

// Column-permuted storage: idx64(c)=(c&15)*4+(c>>4)  (64-wide: hb, ht)
//                          idx128(c)=(c&15)*8+(c>>4) (128-wide: pa, pb, tbl, Sb)
// Weights' K dims are packed with the same permutation, so all GEMMs are invariant.
// Edge record: rec = (src << 12) | ety   (src<2^20, ety<2^12) — single 4 B scatter.
// h is carried in bf16 only (hb).

typedef __attribute__((ext_vector_type(8))) short short8;
typedef __attribute__((ext_vector_type(4))) short short4v;
typedef __attribute__((ext_vector_type(4))) float float4v;

static __device__ __forceinline__ short f2bf(float x) {
  __hip_bfloat16 h = __float2bfloat16(x);
  return *reinterpret_cast<short*>(&h);
}
static __device__ __forceinline__ float bf2f(short s) {
  return __uint_as_float(((unsigned)(unsigned short)s) << 16);
}
static __device__ __forceinline__ float bflo(unsigned u) { return __uint_as_float(u << 16); }
static __device__ __forceinline__ float bfhi(unsigned u) { return __uint_as_float(u & 0xffff0000u); }

// ---------------- init: hb (idx64-permuted) = embed[atoms] ----------------
__global__ void k_init(const int* __restrict__ atoms, const float* __restrict__ embed_w,
                       short* __restrict__ hb, int n) {
  int stride = gridDim.x * blockDim.x;
  for (int i = blockIdx.x * blockDim.x + threadIdx.x; i < n; i += stride) {
    int p = i & 63;
    int col = (p & 3) * 16 + (p >> 2);          // inverse idx64
    hb[i] = f2bf(embed_w[atoms[i >> 6] * NODE_DIM + col]);
  }
}

__global__ void k_zero_f(float* __restrict__ p, int n) {
  int stride = gridDim.x * blockDim.x;
  for (int i = blockIdx.x * blockDim.x + threadIdx.x; i < n; i += stride) p[i] = 0.f;
}
__global__ void k_zero_i(int* __restrict__ p, int n) {
  int i = blockIdx.x * blockDim.x + threadIdx.x;
  if (i < n) p[i] = 0;
}

// ---------------- edge precompute: ety = (kind<<11) | bin(dist); fused dst histogram ----------------
__global__ void k_edge_pre(const int* __restrict__ src, const int* __restrict__ dst,
                           const float* __restrict__ coords, const int* __restrict__ isr,
                           int* __restrict__ ety, int* __restrict__ counts, int E) {
  int stride = gridDim.x * blockDim.x;
  for (int e = blockIdx.x * blockDim.x + threadIdx.x; e < E; e += stride) {
    int s = src[e], d = dst[e];
    float dx = coords[s*3+0] - coords[d*3+0];
    float dy = coords[s*3+1] - coords[d*3+1];
    float dz = coords[s*3+2] - coords[d*3+2];
    float dist = sqrtf(dx*dx + dy*dy + dz*dz);
    int bin = (int)(dist * TBL_SCALE);
    bin = (bin > TBL_BINS - 1) ? TBL_BINS - 1 : bin;
    int kind = (isr[s] != isr[d]) ? 1 : 0;
    ety[e] = (kind << 11) | bin;
    atomicAdd(&counts[d], 1);
  }
}

// ---------------- edge-attr table: thread per OUTPUT ELEMENT (2M threads) ----------------
__global__ void k_tbl(const float* __restrict__ W1, const float* __restrict__ sub_w,
                      short* __restrict__ tbl, int total) {
  int i = blockIdx.x * 256 + threadIdx.x;     // i over [0, L*2*TBL_BINS*128)
  if (i >= total) return;
  int col  = i & 127;
  int idx  = i >> 7;                           // (l, kind, bin)
  int bin  = idx & (TBL_BINS - 1);
  int kind = (idx >> 11) & 1;
  int l    = idx >> 12;
  float dist = ((float)bin + 0.5f) * (1.0f / TBL_SCALE);
  const float* W1c = W1 + (size_t)l * CAT_DIM * HIDDEN + 128 * HIDDEN;
  float acc = 0.f;
  #pragma unroll
  for (int g = 0; g < 16; ++g) {
    float t = dist - (float)g * (1.0f / 3.0f);
    acc += __expf(-4.5f * t * t) * W1c[g * 128 + col];
  }
  #pragma unroll
  for (int g = 0; g < 16; ++g)
    acc += sub_w[kind * 16 + g] * W1c[(16 + g) * 128 + col];
  tbl[(size_t)idx * 128 + (col & 15) * 8 + (col >> 4)] = f2bf(acc);   // idx128
}

// ---------------- CSR build ----------------
__global__ void k_scan_part(const int* __restrict__ counts, int* __restrict__ part, int N) {
  __shared__ int red[256];
  int t = threadIdx.x;
  int i = blockIdx.x * 256 + t;
  red[t] = (i < N) ? counts[i] : 0;
  __syncthreads();
  for (int o = 128; o > 0; o >>= 1) {
    if (t < o) red[t] += red[t + o];
    __syncthreads();
  }
  if (t == 0) part[blockIdx.x] = red[0];
}

__global__ void k_scan_top(int* __restrict__ part, int nb) {
  __shared__ int s[512];
  int t = threadIdx.x;
  int v = (t < nb) ? part[t] : 0;
  s[t] = v;
  __syncthreads();
  for (int o = 1; o < 512; o <<= 1) {
    int u = (t >= o) ? s[t - o] : 0;
    __syncthreads();
    s[t] += u;
    __syncthreads();
  }
  if (t < nb) part[t] = s[t] - v;   // exclusive
}

__global__ void k_scan_apply(const int* __restrict__ counts, const int* __restrict__ part,
                             int* __restrict__ cursor, int* __restrict__ colptr,
                             int N, int E) {
  __shared__ int s[256];
  int t = threadIdx.x;
  int i = blockIdx.x * 256 + t;
  int v = (i < N) ? counts[i] : 0;
  s[t] = v;
  __syncthreads();
  for (int o = 1; o < 256; o <<= 1) {
    int u = (t >= o) ? s[t - o] : 0;
    __syncthreads();
    s[t] += u;
    __syncthreads();
  }
  if (i < N) {
    int ex = part[blockIdx.x] + s[t] - v;   // exclusive prefix
    cursor[i] = ex;
    colptr[i] = ex;
    if (i == N - 1) colptr[N] = E;
  }
}

// scatter packed (src<<12 | ety) records into dst-sorted order (plain 4 B stores)
__global__ void k_build(const int* __restrict__ src, const int* __restrict__ dst,
                        const int* __restrict__ ety, int* __restrict__ cursor,
                        int* __restrict__ sd_p, int E) {
  int stride = gridDim.x * blockDim.x;
  for (int e = blockIdx.x * blockDim.x + threadIdx.x; e < E; e += stride) {
    int d = dst[e];
    int p = atomicAdd(&cursor[d], 1);
    sd_p[p] = (src[e] << 12) | ety[e];
  }
}

// ---------------- weight packing: B-frag order, K permuted to match storage ----------------
__global__ void k_pack_w1ab(const float* __restrict__ W1, short* __restrict__ Wp, int total) {
  int i = blockIdx.x * blockDim.x + threadIdx.x;
  if (i >= total) return;
  int l = i / L1ABSZ, r = i % L1ABSZ;
  int k = r / 256, n = r % 256;                 // k = original h col (0..63)
  int kp = (k & 15) * 4 + (k >> 4);             // idx64
  int kt = kp >> 5, quad = (kp >> 3) & 3, j = kp & 7;
  int srow = (n < 128) ? k : 64 + k;
  int scol = (n < 128) ? n : n - 128;
  Wp[l * L1ABSZ + ((kt*4 + quad) * 256 + n) * 8 + j] =
      f2bf(W1[(size_t)l * CAT_DIM * HIDDEN + srow * HIDDEN + scol]);
}
__global__ void k_pack_w2(const float* __restrict__ W, short* __restrict__ Wp, int total) {
  int i = blockIdx.x * blockDim.x + threadIdx.x;
  if (i >= total) return;
  int l = i / L2SZ, r = i % L2SZ;
  int k = r / NODE_DIM, n = r % NODE_DIM;       // k = original hidden col (0..127)
  int kp = (k & 15) * 8 + (k >> 4);             // idx128
  int kt = kp >> 5, quad = (kp >> 3) & 3, j = kp & 7;
  Wp[l * L2SZ + ((kt*4 + quad) * NODE_DIM + n) * 8 + j] = f2bf(W[i]);
}

// ---------------- node kernel: [agg=Sb@W2+cnt*b2; h=relu(h+agg)] ; [pa|pb = h@W1ab] ----------------
__global__ __launch_bounds__(256, 4) void k_node(
    short* __restrict__ hb,
    const short* __restrict__ Sb, const int* __restrict__ cnts,
    const short* __restrict__ W2p, const float* __restrict__ b2,
    const short* __restrict__ W1abp, const float* __restrict__ b1,
    short* __restrict__ pa, short* __restrict__ pb, int N)
{
  __shared__ short ht[64 * 72];

  const int tid  = threadIdx.x;
  const int lane = tid & 63;
  const int w    = tid >> 6;
  const int quad = lane >> 4;
  const int l16  = lane & 15;
  const int base = blockIdx.x * 64 + w * 16;

  if (W2p) {
    float4v acc[4];
    #pragma unroll
    for (int nt = 0; nt < 4; ++nt) acc[nt] = (float4v)0.f;
    const int arow = base + l16;
    const bool av = arow < N;
    #pragma unroll
    for (int kt = 0; kt < 4; ++kt) {
      short8 a = av ? *(const short8*)&Sb[(size_t)arow * 128 + kt*32 + quad*8]
                    : (short8)0;
      #pragma unroll
      for (int nt = 0; nt < 4; ++nt) {
        short8 b = *(const short8*)&W2p[((kt*4 + quad) * NODE_DIM + nt*16 + l16) * 8];
        acc[nt] = __builtin_amdgcn_mfma_f32_16x16x32_bf16(a, b, acc[nt], 0, 0, 0);
      }
    }
    float bb[4];
    #pragma unroll
    for (int nt = 0; nt < 4; ++nt) bb[nt] = b2[nt*16 + l16];
    #pragma unroll
    for (int r = 0; r < 4; ++r) {
      int row  = base + quad*4 + r;
      int lrow = w*16 + quad*4 + r;
      if (row < N) {
        float cf = (float)cnts[row];
        short4v hv = *(const short4v*)&hb[(size_t)row * 64 + l16*4];  // permuted pos l16*4+nt
        float v0 = fmaxf(bf2f(hv[0]) + acc[0][r] + cf * bb[0], 0.f);
        float v1 = fmaxf(bf2f(hv[1]) + acc[1][r] + cf * bb[1], 0.f);
        float v2 = fmaxf(bf2f(hv[2]) + acc[2][r] + cf * bb[2], 0.f);
        float v3 = fmaxf(bf2f(hv[3]) + acc[3][r] + cf * bb[3], 0.f);
        short4v hs = {f2bf(v0), f2bf(v1), f2bf(v2), f2bf(v3)};
        *(short4v*)&hb[(size_t)row * 64 + l16*4] = hs;
        *(short4v*)&ht[lrow * 72 + l16*4] = hs;
      } else {
        *(short4v*)&ht[lrow * 72 + l16*4] = (short4v)0;
      }
    }
  } else {
    int row = base + l16;
    #pragma unroll
    for (int c = 0; c < 2; ++c) {
      int colc = quad*16 + c*8;
      short8 v = (row < N) ? *(const short8*)&hb[(size_t)row * 64 + colc] : (short8)0;
      *(short8*)&ht[(w*16 + l16) * 72 + colc] = v;
    }
  }

  if (W1abp) {
    float4v acc[16];
    #pragma unroll
    for (int nt = 0; nt < 16; ++nt) acc[nt] = (float4v)0.f;
    #pragma unroll
    for (int kt = 0; kt < 2; ++kt) {
      short8 a = *(const short8*)&ht[(w*16 + l16) * 72 + kt*32 + quad*8];
      #pragma unroll
      for (int nt = 0; nt < 16; ++nt) {
        short8 b = *(const short8*)&W1abp[((kt*4 + quad) * 256 + nt*16 + l16) * 8];
        acc[nt] = __builtin_amdgcn_mfma_f32_16x16x32_bf16(a, b, acc[nt], 0, 0, 0);
      }
    }
    float b1a[8];
    #pragma unroll
    for (int nt = 0; nt < 8; ++nt) b1a[nt] = b1[nt*16 + l16];
    #pragma unroll
    for (int r = 0; r < 4; ++r) {
      int row = base + quad*4 + r;
      if (row < N) {
        short8 va, vb;
        #pragma unroll
        for (int nt = 0; nt < 8; ++nt) va[nt] = f2bf(acc[nt][r] + b1a[nt]);
        #pragma unroll
        for (int nt = 0; nt < 8; ++nt) vb[nt] = f2bf(acc[nt + 8][r]);
        *(short8*)&pa[(size_t)row * 128 + l16*8] = va;   // permuted pos l16*8+nt
        *(short8*)&pb[(size_t)row * 128 + l16*8] = vb;
      }
    }
  }
}

// ---------------- gather kernel: wave per node, 4-deep double-buffered CSR gather ----------------
__global__ __launch_bounds__(256, 8) void k_gather(
    const short* __restrict__ pa, const short* __restrict__ pb,
    const short* __restrict__ tblL,
    const int* __restrict__ sd_p, const int* __restrict__ colptr,
    short* __restrict__ Sb, int N)
{
  int n = blockIdx.x * 4 + (threadIdx.x >> 6);
  if (n >= N) return;
  const int lane = threadIdx.x & 63;
  const int d2 = lane * 2;

  const int s = colptr[n];
  const int e = colptr[n + 1];

  unsigned up = *(const unsigned*)&pa[(size_t)n * 128 + d2];
  const float p0 = bflo(up), p1 = bfhi(up);
  float s0 = 0.f, s1 = 0.f;

  const char* pbB = (const char*)pb + d2 * 2;
  const char* tbB = (const char*)tblL + d2 * 2;

  if (e > s) {
    unsigned ub0[4], ue0[4], ub1[4], ue1[4];

    auto load4 = [&](unsigned (&ub)[4], unsigned (&ue)[4], int j) {
      #pragma unroll
      for (int t = 0; t < 4; ++t) {
        int jj = (j + t < e) ? j + t : s;       // clamp: always a valid record
        int rc = __builtin_amdgcn_readfirstlane(sd_p[jj]);  // wave-uniform scalar
        int so = (rc >> 12) << 8;               // src byte offset (256 B rows)
        int to = (rc & 0xfff) << 8;             // ety byte offset
        ub[t] = *(const unsigned*)(pbB + so);
        ue[t] = *(const unsigned*)(tbB + to);
      }
    };
    auto consume4 = [&](unsigned (&ub)[4], unsigned (&ue)[4], int j) {
      #pragma unroll
      for (int t = 0; t < 4; ++t) {
        if (j + t < e) {
          float x0 = p0 + bflo(ub[t]) + bflo(ue[t]);
          float x1 = p1 + bfhi(ub[t]) + bfhi(ue[t]);
          s0 += x0 * __builtin_amdgcn_rcpf(1.f + __expf(-x0));
          s1 += x1 * __builtin_amdgcn_rcpf(1.f + __expf(-x1));
        }
      }
    };

    load4(ub0, ue0, s);
    int j = s;
    for (; j + 4 < e; j += 8) {
      load4(ub1, ue1, j + 4);
      consume4(ub0, ue0, j);
      if (j + 8 < e) load4(ub0, ue0, j + 8);
      consume4(ub1, ue1, j + 4);
    }
    if (j < e) consume4(ub0, ue0, j);
  }

  unsigned pk = ((unsigned)(unsigned short)f2bf(s1) << 16) | (unsigned short)f2bf(s0);
  *(unsigned*)&Sb[(size_t)n * 128 + d2] = pk;
}

// ---------------- mean pool (batch_ids sorted): wave per 64 nodes, bf16 h ----------------
__global__ void k_pool(const short* __restrict__ hb, const int* __restrict__ batch_ids,
                       float* __restrict__ pooled, float* __restrict__ counts, int N) {
  int lane = threadIdx.x & 63;
  int base = blockIdx.x * 64;
  float acc = 0.f;
  int   cnt = 0;
  int  gcur = -1;
  for (int n = 0; n < 64; ++n) {
    int node = base + n;
    if (node >= N) break;
    int g = batch_ids[node];
    if (g != gcur) {
      if (gcur >= 0) {
        atomicAdd(&pooled[gcur * NODE_DIM + lane], acc);
        if (lane == 0) atomicAdd(&counts[gcur], (float)cnt);
      }
      gcur = g; acc = 0.f; cnt = 0;
    }
    acc += bf2f(hb[(size_t)node * NODE_DIM + lane]);
    cnt++;
  }
  if (gcur >= 0) {
    atomicAdd(&pooled[gcur * NODE_DIM + lane], acc);
    if (lane == 0) atomicAdd(&counts[gcur], (float)cnt);
  }
}

// final linear: un-permute fc_w (pooled is idx64-permuted)
__global__ void k_final(const float* __restrict__ pooled, const float* __restrict__ counts,
                        const float* __restrict__ fc_w, const float* __restrict__ fc_b,
                        float* __restrict__ out, int G) {
  int g = blockIdx.x * blockDim.x + threadIdx.x;
  if (g < G) {
    float acc = 0.f;
    for (int d = 0; d < NODE_DIM; ++d) {
      int col = (d & 3) * 16 + (d >> 2);      // inverse idx64
      acc += pooled[g * NODE_DIM + d] * fc_w[col];
    }
    float c = counts[g];
    if (c < 1.f) c = 1.f;
    out[g] = acc / c + fc_b[0];
  }
}

extern "C" void kernel_launch(void* const* d_in, const int* in_sizes, int n_in,
                              void* d_out, int out_size, void* d_ws, size_t ws_size,
                              hipStream_t stream) {
  const int*   atoms   = (const int*)  d_in[0];
  const int*   eidx    = (const int*)  d_in[1];
  const float* coords  = (const float*)d_in[2];
  const int*   isr     = (const int*)  d_in[3];
  const int*   batch   = (const int*)  d_in[4];
  const float* embed_w = (const float*)d_in[5];
  const float* sub_w   = (const float*)d_in[6];
  const float* W1      = (const float*)d_in[7];
  const float* b1      = (const float*)d_in[8];
  const float* W2      = (const float*)d_in[9];
  const float* b2      = (const float*)d_in[10];
  const float* fc_w    = (const float*)d_in[11];
  const float* fc_b    = (const float*)d_in[12];
  float* out = (float*)d_out;

  const int N = in_sizes[0];
  const int E = in_sizes[1] / 2;
  const int L = in_sizes[8] / HIDDEN;
  const int G = out_size;

  const int* srcv = eidx;
  const int* dstv = eidx + E;

  size_t off = 0;
  auto carve = [&](size_t bytes) -> char* {
    char* p = (char*)d_ws + off;
    off += (bytes + 255) & ~(size_t)255;
    return p;
  };
  short* hb     = (short*)carve((size_t)N * NODE_DIM * 2);
  short* Sb     = (short*)carve((size_t)N * HIDDEN * 2);
  short* pa     = (short*)carve((size_t)N * HIDDEN * 2);
  short* pb     = (short*)carve((size_t)N * HIDDEN * 2);
  int*   ety    = (int*)  carve((size_t)E * 4);
  int*   cnts   = (int*)  carve((size_t)N * 4);
  int*   cursor = (int*)  carve((size_t)N * 4);
  int*   colptr = (int*)  carve(((size_t)N + 2) * 4);
  int*   sd_p   = (int*)  carve((size_t)E * 4);
  int*   part   = (int*)  carve(((size_t)N / 256 + 2) * 4);
  short* W1abp  = (short*)carve((size_t)L * L1ABSZ * 2);
  short* W2p    = (short*)carve((size_t)L * L2SZ * 2);
  short* tbl    = (short*)carve((size_t)L * TBLSZ * 2);
  float* pooled = (float*)carve((size_t)G * NODE_DIM * 4);
  float* cntg   = (float*)carve((size_t)G * 4);

  const int nbN = (N + 255) / 256;

  k_zero_i<<<nbN, 256, 0, stream>>>(cnts, N);
  k_init<<<1024, 256, 0, stream>>>(atoms, embed_w, hb, N * NODE_DIM);
  k_edge_pre<<<4096, 256, 0, stream>>>(srcv, dstv, coords, isr, ety, cnts, E);
  k_zero_f<<<(G * NODE_DIM + G + 255) / 256, 256, 0, stream>>>(pooled, G * NODE_DIM + G);
  k_scan_part<<<nbN, 256, 0, stream>>>(cnts, part, N);
  k_scan_top<<<1, 512, 0, stream>>>(part, nbN);
  k_scan_apply<<<nbN, 256, 0, stream>>>(cnts, part, cursor, colptr, N, E);
  k_build<<<4096, 256, 0, stream>>>(srcv, dstv, ety, cursor, sd_p, E);
  k_pack_w1ab<<<(L * L1ABSZ + 255) / 256, 256, 0, stream>>>(W1, W1abp, L * L1ABSZ);
  k_pack_w2<<<(L * L2SZ + 255) / 256, 256, 0, stream>>>(W2, W2p, L * L2SZ);
  k_tbl<<<(L * 2 * TBL_BINS * 128 + 255) / 256, 256, 0, stream>>>(W1, sub_w, tbl,
                                                                  L * 2 * TBL_BINS * 128);

  const int nblk_n = (N + 63) / 64;
  const int nblk_g = (N + 3) / 4;
  for (int l = 0; l < L; ++l) {
    k_node<<<nblk_n, 256, 0, stream>>>(
        hb, Sb, cnts,
        (l > 0) ? W2p + (size_t)(l - 1) * L2SZ : (const short*)nullptr,
        (l > 0) ? b2 + (size_t)(l - 1) * NODE_DIM : (const float*)nullptr,
        W1abp + (size_t)l * L1ABSZ, b1 + (size_t)l * HIDDEN,
        pa, pb, N);
    k_gather<<<nblk_g, 256, 0, stream>>>(pa, pb, tbl + (size_t)l * TBLSZ,
                                         sd_p, colptr, Sb, N);
  }
  k_node<<<nblk_n, 256, 0, stream>>>(
      hb, Sb, cnts,
      W2p + (size_t)(L - 1) * L2SZ, b2 + (size_t)(L - 1) * NODE_DIM,
      (const short*)nullptr, (const float*)nullptr, pa, pb, N);

  k_pool<<<(N + 63) / 64, 64, 0, stream>>>(hb, batch, pooled, cntg, N);
  k_final<<<1, 64, 0, stream>>>(pooled, cntg, fc_w, fc_b, out, G);
}